// Round 2
// baseline (46384.015 us; speedup 1.0000x reference)
//
#include <hip/hip_runtime.h>
#include <stdint.h>
#include <math.h>

// Problem: B=256, C=4, N=256, PSI=0.05
// out[b][c] = Q_log(0.95 * S_c x_b S_c + 0.05 I),  S_c = Q_rsqrt(0.95 W_c + 0.05 I)
// mat index = b*4 + c  (matches out[b][c] contiguity)
//
// Workspace layout (float offsets), runtime-chunked by CS matrices:
//   S    : 4*65536   S_c matrices
//   Wp   : 4*65536   W' (perm layout)
//   V    : CS*32768  packed Householder reflectors
//   tau  : CS*256
//   d    : CS*256    tridiag diagonal
//   e    : CS*256    tridiag subdiagonal
//   lam  : CS*256    eigenvalues (sorted)
//   EG   : CS*65536  P / E / G (phase-shared)
// bytes = 4*(524288 + CS*99328); CS=1024 -> ~409 MB, CS=256 -> ~103 MB.

__device__ __forceinline__ int tp_voff(int k) { return 255*k - (k*(k-1))/2; }

__device__ __forceinline__ float tp_hashf(uint32_t a) {
    a ^= a >> 16; a *= 0x7feb352du; a ^= a >> 15; a *= 0x846ca68bu; a ^= a >> 16;
    return (float)(a & 0xFFFFFFu) * (1.0f/16777216.0f) - 0.5f;
}

// permuted layout used as tridiag input: owner thread tt = i + (j>>7)*256,
// float offset = ((j&127)>>2)*2048 + tt*4 + (j&3). Bijective on 65536.

// ---------------------------------------------------------------------------
// W' = 0.95 W + 0.05 I  (write in permuted layout)
__global__ __launch_bounds__(256)
void tp_regw(const float* __restrict__ W, float* __restrict__ Wp)
{
    int g = blockIdx.x * 256 + threadIdx.x;          // 0 .. 262143
    int c = g >> 16, o = g & 65535;
    int jo = o >> 11, rrem = o & 2047, tt = rrem >> 2, ji = rrem & 3;
    int i = tt & 255;
    int j = ((tt >> 8) << 7) + (jo << 2) + ji;
    Wp[g] = 0.95f * W[c*65536 + i*256 + j] + ((i == j) ? 0.05f : 0.0f);
}

// ---------------------------------------------------------------------------
// Householder tridiagonalization. One matrix per 512-thread block; full
// symmetric matrix in registers: thread t owns row (t&255), cols (t>>8)*128..+127.
__global__ __launch_bounds__(512, 1)
void tp_tridiag(const float* __restrict__ Min, float* __restrict__ V,
                float* __restrict__ taug, float* __restrict__ dg,
                float* __restrict__ eg)
{
    const int mat = blockIdx.x;
    const int t   = threadIdx.x;
    const int row = t & 255;
    const int rh  = t >> 8;
    const int cb  = rh << 7;

    const float4* M4 = (const float4*)(Min + (size_t)mat * 65536);
    float* Vb = V + (size_t)mat * 32768;

    __shared__ __align__(16) float pivot[256];
    __shared__ __align__(16) float p2[2][256];
    __shared__ __align__(16) float vv[256];
    __shared__ __align__(16) float ww[256];

    float A[128];
#pragma unroll
    for (int jo = 0; jo < 32; ++jo) {
        float4 v4 = M4[jo * 512 + t];
        A[jo*4+0]=v4.x; A[jo*4+1]=v4.y; A[jo*4+2]=v4.z; A[jo*4+3]=v4.w;
    }
    if (t < 256) { vv[t] = 0.f; ww[t] = 0.f; }
    if (rh == 0) pivot[row] = A[0];            // column 0
    if (t == 0)  dg[mat*256] = A[0];
    __syncthreads();

    const int lane = t & 63;
    for (int k = 0; k < 254; ++k) {
        // ---- Householder scalars (redundant per wave; pivot = col k) ----
        float sig = 0.f;
        for (int i = k + 2 + lane; i < 256; i += 64) { float x = pivot[i]; sig = fmaf(x, x, sig); }
#pragma unroll
        for (int off = 32; off; off >>= 1) sig += __shfl_xor(sig, off);
        float alpha = pivot[k+1];
        float beta, tu, s;
        if (sig <= 1e-36f) { beta = alpha; tu = 0.f; s = 0.f; }
        else {
            beta = -copysignf(sqrtf(fmaf(alpha, alpha, sig)), alpha);
            tu   = (beta - alpha) / beta;
            s    = 1.f / (alpha - beta);
        }
        // ---- v (vv stays zero outside (k,255]) + packed V store ----
        if (t < 256) {
            int j = t;
            if (j == k) { vv[j] = 0.f; ww[j] = 0.f; }
            else if (j > k) {
                float val = (j == k+1) ? ((tu != 0.f) ? 1.f : 0.f) : pivot[j] * s;
                vv[j] = val;
                Vb[tp_voff(k) + (j - k - 1)] = val;
            }
        }
        if (t == 0) { taug[mat*256+k] = tu; eg[mat*256+k] = beta; }
        __syncthreads();
        // ---- p = A * v (no masking needed: vv is zero on dead cols) ----
        if (row > k) {
            float part = 0.f;
#pragma unroll
            for (int blk = 0; blk < 8; ++blk) {
                if (cb + blk*16 + 15 > k) {
#pragma unroll
                    for (int q = 0; q < 16; q += 4) {
                        float4 v4 = *(const float4*)&vv[cb + blk*16 + q];
                        part = fmaf(A[blk*16+q+0], v4.x, part);
                        part = fmaf(A[blk*16+q+1], v4.y, part);
                        part = fmaf(A[blk*16+q+2], v4.z, part);
                        part = fmaf(A[blk*16+q+3], v4.w, part);
                    }
                }
            }
            p2[rh][row] = part;
        }
        __syncthreads();
        // ---- w = tau*p - (tau^2 (v.p)/2) v ----
        float s2 = 0.f;
        for (int i = k + 1 + lane; i < 256; i += 64) s2 = fmaf(vv[i], p2[0][i] + p2[1][i], s2);
#pragma unroll
        for (int off = 32; off; off >>= 1) s2 += __shfl_xor(s2, off);
        float cc = 0.5f * tu * tu * s2;
        if (t < 256 && t > k) ww[t] = tu * (p2[0][t] + p2[1][t]) - cc * vv[t];
        __syncthreads();
        // ---- A -= v w^T + w v^T ; extract next pivot column k+1 ----
        if (row > k) {
            float vr = vv[row], wr = ww[row];
#pragma unroll
            for (int blk = 0; blk < 8; ++blk) {
                if (cb + blk*16 + 15 > k) {
#pragma unroll
                    for (int q = 0; q < 16; q += 4) {
                        float4 v4 = *(const float4*)&vv[cb + blk*16 + q];
                        float4 w4 = *(const float4*)&ww[cb + blk*16 + q];
                        float n0 = A[blk*16+q+0] - (vr*w4.x + wr*v4.x);
                        float n1 = A[blk*16+q+1] - (vr*w4.y + wr*v4.y);
                        float n2 = A[blk*16+q+2] - (vr*w4.z + wr*v4.z);
                        float n3 = A[blk*16+q+3] - (vr*w4.w + wr*v4.w);
                        A[blk*16+q+0] = n0; A[blk*16+q+1] = n1;
                        A[blk*16+q+2] = n2; A[blk*16+q+3] = n3;
                        const int jj = cb + blk*16 + q;      // wave-uniform
                        if (jj+0 == k+1) { pivot[row] = n0; if (row == k+1) dg[mat*256+k+1] = n0; }
                        if (jj+1 == k+1) { pivot[row] = n1; if (row == k+1) dg[mat*256+k+1] = n1; }
                        if (jj+2 == k+1) { pivot[row] = n2; if (row == k+1) dg[mat*256+k+1] = n2; }
                        if (jj+3 == k+1) { pivot[row] = n3; if (row == k+1) dg[mat*256+k+1] = n3; }
                    }
                }
            }
        }
        __syncthreads();
    }
    if (t == 0)   eg[mat*256+254] = pivot[255];   // A[255][254]
    if (t == 511) dg[mat*256+255] = A[127];       // A[255][255]
}

// ---------------------------------------------------------------------------
// All 256 eigenvalues by Sturm bisection; thread t -> t-th smallest (sorted).
__global__ __launch_bounds__(256)
void tp_bisect(const float* __restrict__ dg, const float* __restrict__ eg,
               float* __restrict__ lam)
{
    const int mat = blockIdx.x, t = threadIdx.x;
    __shared__ float d[256], e2[256];
    __shared__ float redmin[4], redmax[4];
    float dt = dg[mat*256+t];
    float et = (t < 255) ? eg[mat*256+t] : 0.f;
    d[t] = dt; e2[t] = et*et;
    float ep = (t > 0) ? eg[mat*256+t-1] : 0.f;
    float r = fabsf(et) + fabsf(ep);
    float lo = dt - r, hi = dt + r;
#pragma unroll
    for (int off = 32; off; off >>= 1) {
        lo = fminf(lo, __shfl_xor(lo, off));
        hi = fmaxf(hi, __shfl_xor(hi, off));
    }
    if ((t & 63) == 0) { redmin[t>>6] = lo; redmax[t>>6] = hi; }
    __syncthreads();
    float gl = fminf(fminf(redmin[0],redmin[1]), fminf(redmin[2],redmin[3]));
    float gu = fmaxf(fmaxf(redmax[0],redmax[1]), fmaxf(redmax[2],redmax[3]));
    float rng = gu - gl;
    gl -= 1e-6f*rng + 1e-30f; gu += 1e-6f*rng + 1e-30f;
    const float PIVB = 1e-30f;
    float l = gl, u = gu;
    for (int it = 0; it < 42; ++it) {
        float mid = 0.5f*(l+u);
        float q = d[0] - mid;
        if (fabsf(q) < PIVB) q = -PIVB;
        int cnt = (q < 0.f);
        for (int i = 1; i < 256; ++i) {
            q = d[i] - mid - e2[i-1]/q;
            if (fabsf(q) < PIVB) q = -PIVB;
            cnt += (q < 0.f);
        }
        if (cnt <= t) l = mid; else u = mid;
    }
    lam[mat*256+t] = 0.5f*(l+u);
}

// ---------------------------------------------------------------------------
// Inverse iteration on T (LDL^T solve), 64 eigenvectors per 64-thread block.
// Dynamic LDS: v[256][64], r[256][64], d[256], e[256] = 133120 bytes.
__global__ __launch_bounds__(64)
void tp_invit(const float* __restrict__ dg, const float* __restrict__ eg,
              const float* __restrict__ lam, float* __restrict__ E)
{
    extern __shared__ float ls[];
    float* vb = ls;              // [256][64]
    float* rb = ls + 16384;      // [256][64]
    float* d  = ls + 32768;      // 256
    float* e  = ls + 33024;      // 256 (e[255]=0)
    const int mat = blockIdx.x >> 2;
    const int t = threadIdx.x;
    const int vecid = ((blockIdx.x & 3) << 6) | t;
    for (int i = t; i < 256; i += 64) {
        d[i] = dg[mat*256+i];
        e[i] = (i < 255) ? eg[mat*256+i] : 0.f;
    }
    __syncthreads();
    float mx = 0.f;
    for (int i = t; i < 256; i += 64) mx = fmaxf(mx, fabsf(d[i]) + 2.f*fabsf(e[i]));
#pragma unroll
    for (int off = 32; off; off >>= 1) mx = fmaxf(mx, __shfl_xor(mx, off));
    const float piv = fmaxf(mx, 1e-10f) * 1e-8f;
    const float sigma = lam[mat*256 + vecid];
    const uint32_t sd = ((uint32_t)(mat*256 + vecid) << 9) + 12345u;
    for (int i = 0; i < 256; ++i) vb[i*64+t] = tp_hashf(sd + (uint32_t)i);

    for (int iter = 0; iter < 2; ++iter) {
        float rp, y;
        if (iter == 0) {
            float del = d[0] - sigma;
            if (fabsf(del) < piv) del = copysignf(piv, del);
            rp = 1.f / del; rb[t] = rp;
        } else rp = rb[t];
        y = vb[t];
        for (int i = 1; i < 256; ++i) {
            float ei = e[i-1];
            float lmul = ei * rp;
            float ri;
            if (iter == 0) {
                float dl = (d[i] - sigma) - lmul * ei;
                if (fabsf(dl) < piv) dl = copysignf(piv, dl);
                ri = 1.f / dl; rb[i*64+t] = ri;
            } else ri = rb[i*64+t];
            y = vb[i*64+t] - lmul * y;
            vb[i*64+t] = y;
            rp = ri;
        }
        float vn = vb[255*64+t] * rb[255*64+t];
        vb[255*64+t] = vn;
        float nrm = vn*vn;
        for (int i = 254; i >= 0; --i) {
            float vi = (vb[i*64+t] - e[i]*vn) * rb[i*64+t];
            vb[i*64+t] = vi; vn = vi;
            nrm = fmaf(vi, vi, nrm);
        }
        if (!(nrm > 1e-30f && nrm < 1e37f)) {     // breakdown / overflow guard
            for (int i = 0; i < 256; ++i) vb[i*64+t] = (i == vecid) ? 1.f : 0.f;
        } else {
            float sc = rsqrtf(nrm);
            for (int i = 0; i < 256; ++i) vb[i*64+t] *= sc;
        }
    }
    float* Eb = E + (size_t)mat*65536;
    for (int i = 0; i < 256; ++i) Eb[i*256 + vecid] = vb[i*64+t];   // E[comp][vec]
}

// ---------------------------------------------------------------------------
// MGS re-orthogonalization inside eigenvalue clusters (gap < 6e-5 * range).
__global__ __launch_bounds__(256)
void tp_reorth(const float* __restrict__ lam, float* __restrict__ E)
{
    const int mat = blockIdx.x, t = threadIdx.x;
    __shared__ float l[256];
    __shared__ int astart[256];
    __shared__ float rbuf2[256];
    l[t] = lam[mat*256+t];
    __syncthreads();
    if (t == 0) {
        float thr = 6e-5f * (l[255] - l[0]) + 1e-30f;
        astart[0] = 0;
        for (int j = 1; j < 256; ++j)
            astart[j] = (l[j] - l[j-1] < thr) ? astart[j-1] : j;
    }
    __syncthreads();
    float* Eb = E + (size_t)mat*65536;
    for (int j = 1; j < 256; ++j) {
        if (astart[j] == j) continue;             // uniform
        float xj = Eb[t*256 + j];
        for (int i = astart[j]; i < j; ++i) {
            float xi = Eb[t*256 + i];
            __syncthreads();
            rbuf2[t] = xi * xj;
            __syncthreads();
            if (t < 128) rbuf2[t] += rbuf2[t+128];
            __syncthreads();
            if (t < 64)  rbuf2[t] += rbuf2[t+64];
            __syncthreads();
            if (t == 0) { float ss = 0.f; for (int q = 0; q < 64; ++q) ss += rbuf2[q]; rbuf2[0] = ss; }
            __syncthreads();
            xj -= rbuf2[0] * xi;
        }
        __syncthreads();
        rbuf2[t] = xj * xj;
        __syncthreads();
        if (t < 128) rbuf2[t] += rbuf2[t+128];
        __syncthreads();
        if (t < 64)  rbuf2[t] += rbuf2[t+64];
        __syncthreads();
        if (t == 0) { float ss = 0.f; for (int q = 0; q < 64; ++q) ss += rbuf2[q]; rbuf2[0] = ss; }
        __syncthreads();
        float nrm = rbuf2[0];
        if (nrm > 1e-30f) xj *= rsqrtf(nrm);
        Eb[t*256 + j] = xj;
        __syncthreads();
    }
}

// ---------------------------------------------------------------------------
// Back-transform: G = H_0 ... H_253 E (apply reflectors in reverse order).
// Thread t owns column (t&255), rows (t>>8)*128..+127 in registers.
__global__ __launch_bounds__(512, 1)
void tp_backxf(float* __restrict__ E, const float* __restrict__ V,
               const float* __restrict__ taug)
{
    const int mat = blockIdx.x, t = threadIdx.x;
    const int j = t & 255, rh = t >> 8;
    float* Eb = E + (size_t)mat*65536;
    const float* Vb = V + (size_t)mat*32768;
    const float* taub = taug + mat*256;
    __shared__ __align__(16) float vbuf[2][256];
    __shared__ float part[2][256];
    __shared__ float taush[2];
    float Er[128];
#pragma unroll
    for (int r = 0; r < 128; ++r) Er[r] = Eb[(rh*128 + r)*256 + j];
    ((float*)vbuf)[t & 511] = 0.f;                 // zero both buffers (512 floats)
    __syncthreads();
    if (t < 2) vbuf[0][254 + t] = Vb[tp_voff(253) + t];
    if (t == 0) taush[0] = taub[253];
    for (int k = 253; k >= 0; --k) {
        const int cur = (253 - k) & 1;
        __syncthreads();                           // vbuf[cur]/taush[cur] ready
        const float tu = taush[cur];
        float p = 0.f;
#pragma unroll
        for (int blk = 0; blk < 8; ++blk) {
            const int rbase = rh*128 + blk*16;
            if (rbase + 15 > k) {                  // rows <= k read zeros anyway
#pragma unroll
                for (int q = 0; q < 16; q += 4) {
                    float4 v4 = *(const float4*)&vbuf[cur][rbase + q];
                    p = fmaf(Er[blk*16+q+0], v4.x, p);
                    p = fmaf(Er[blk*16+q+1], v4.y, p);
                    p = fmaf(Er[blk*16+q+2], v4.z, p);
                    p = fmaf(Er[blk*16+q+3], v4.w, p);
                }
            }
        }
        part[rh][j] = p;
        __syncthreads();
        const float sj = (part[0][j] + part[1][j]) * tu;
        if (k > 0) {                               // prefetch next reflector
            const int kn = k - 1, len = 255 - kn, vo = tp_voff(kn);
            for (int idx = t; idx < len; idx += 512)
                vbuf[cur^1][kn+1+idx] = Vb[vo + idx];
            if (t == 0) taush[cur^1] = taub[kn];
        }
#pragma unroll
        for (int blk = 0; blk < 8; ++blk) {
            const int rbase = rh*128 + blk*16;
            if (rbase + 15 > k) {
#pragma unroll
                for (int q = 0; q < 16; q += 4) {
                    float4 v4 = *(const float4*)&vbuf[cur][rbase + q];
                    Er[blk*16+q+0] = fmaf(-sj, v4.x, Er[blk*16+q+0]);
                    Er[blk*16+q+1] = fmaf(-sj, v4.y, Er[blk*16+q+1]);
                    Er[blk*16+q+2] = fmaf(-sj, v4.z, Er[blk*16+q+2]);
                    Er[blk*16+q+3] = fmaf(-sj, v4.w, Er[blk*16+q+3]);
                }
            }
        }
    }
#pragma unroll
    for (int r = 0; r < 128; ++r) Eb[(rh*128 + r)*256 + j] = Er[r];
}

// ---------------------------------------------------------------------------
// fp32 128x128-tile GEMMs (256 thr, 8x8 micro-tile, K-step 16)
#define GEMM_PROLOGUE(Aptr, Bptr)                                              \
    __shared__ __align__(16) float As[16][132];                                \
    __shared__ __align__(16) float Bs[16][132];                                \
    const int t = threadIdx.x, tx = t & 15, ty = t >> 4;                       \
    const int li = t >> 1, lk = (t & 1) * 8;                                   \
    const int bk = t >> 4, bj = (t & 15) * 8;                                  \
    float acc[8][8];                                                           \
    _Pragma("unroll") for (int q = 0; q < 8; ++q)                              \
    _Pragma("unroll") for (int r2 = 0; r2 < 8; ++r2) acc[q][r2] = 0.f;

#define GEMM_INNER                                                             \
    _Pragma("unroll")                                                          \
    for (int kk = 0; kk < 16; ++kk) {                                          \
        float4 av0 = *(const float4*)&As[kk][ty*8];                            \
        float4 av1 = *(const float4*)&As[kk][ty*8+4];                          \
        float4 bv0 = *(const float4*)&Bs[kk][tx*8];                            \
        float4 bv1 = *(const float4*)&Bs[kk][tx*8+4];                          \
        float av[8] = {av0.x,av0.y,av0.z,av0.w,av1.x,av1.y,av1.z,av1.w};       \
        float bw[8] = {bv0.x,bv0.y,bv0.z,bv0.w,bv1.x,bv1.y,bv1.z,bv1.w};       \
        _Pragma("unroll") for (int q = 0; q < 8; ++q)                          \
        _Pragma("unroll") for (int r2 = 0; r2 < 8; ++r2)                       \
            acc[q][r2] = fmaf(av[q], bw[r2], acc[q][r2]);                      \
    }

// P[lm] = x_b @ S_c,  gm = mat0 + lm
__global__ __launch_bounds__(256)
void tp_gemm_xS(const float* __restrict__ X, const float* __restrict__ S,
                float* __restrict__ P, int mat0)
{
    const int lm = blockIdx.y, gm = mat0 + lm, b = gm >> 2, c = gm & 3;
    const int i0 = (blockIdx.x >> 1) * 128, j0 = (blockIdx.x & 1) * 128;
    const float* Ag = X + (size_t)b * 65536;
    const float* Bg = S + (size_t)c * 65536;
    float* Cg = P + (size_t)lm * 65536;
    GEMM_PROLOGUE(Ag, Bg)
    for (int k0 = 0; k0 < 256; k0 += 16) {
        float4 a0 = *(const float4*)&Ag[(i0+li)*256 + k0 + lk];
        float4 a1 = *(const float4*)&Ag[(i0+li)*256 + k0 + lk + 4];
        float4 b0 = *(const float4*)&Bg[(k0+bk)*256 + j0 + bj];
        float4 b1 = *(const float4*)&Bg[(k0+bk)*256 + j0 + bj + 4];
        __syncthreads();
        As[lk+0][li]=a0.x; As[lk+1][li]=a0.y; As[lk+2][li]=a0.z; As[lk+3][li]=a0.w;
        As[lk+4][li]=a1.x; As[lk+5][li]=a1.y; As[lk+6][li]=a1.z; As[lk+7][li]=a1.w;
        *(float4*)&Bs[bk][bj] = b0;  *(float4*)&Bs[bk][bj+4] = b1;
        __syncthreads();
        GEMM_INNER
    }
#pragma unroll
    for (int q = 0; q < 8; ++q) {
        float4 o0 = {acc[q][0],acc[q][1],acc[q][2],acc[q][3]};
        float4 o1 = {acc[q][4],acc[q][5],acc[q][6],acc[q][7]};
        *(float4*)&Cg[(i0+ty*8+q)*256 + j0 + tx*8]     = o0;
        *(float4*)&Cg[(i0+ty*8+q)*256 + j0 + tx*8 + 4] = o1;
    }
}

// M[lm] = 0.95 * S_c @ P[lm] + 0.05 I -> permuted layout (Mout pre-offset;
// requires mat0 % 4 == 0 so c = lm & 3)
__global__ __launch_bounds__(256)
void tp_gemm_SP(const float* __restrict__ S, const float* __restrict__ P,
                float* __restrict__ Mout)
{
    const int lm = blockIdx.y, c = lm & 3;
    const int i0 = (blockIdx.x >> 1) * 128, j0 = (blockIdx.x & 1) * 128;
    const float* Ag = S + (size_t)c * 65536;
    const float* Bg = P + (size_t)lm * 65536;
    float* Mb = Mout + (size_t)lm * 65536;
    GEMM_PROLOGUE(Ag, Bg)
    for (int k0 = 0; k0 < 256; k0 += 16) {
        float4 a0 = *(const float4*)&Ag[(i0+li)*256 + k0 + lk];
        float4 a1 = *(const float4*)&Ag[(i0+li)*256 + k0 + lk + 4];
        float4 b0 = *(const float4*)&Bg[(k0+bk)*256 + j0 + bj];
        float4 b1 = *(const float4*)&Bg[(k0+bk)*256 + j0 + bj + 4];
        __syncthreads();
        As[lk+0][li]=a0.x; As[lk+1][li]=a0.y; As[lk+2][li]=a0.z; As[lk+3][li]=a0.w;
        As[lk+4][li]=a1.x; As[lk+5][li]=a1.y; As[lk+6][li]=a1.z; As[lk+7][li]=a1.w;
        *(float4*)&Bs[bk][bj] = b0;  *(float4*)&Bs[bk][bj+4] = b1;
        __syncthreads();
        GEMM_INNER
    }
#pragma unroll
    for (int q = 0; q < 8; ++q) {
        const int i = i0 + ty*8 + q;
        const int jb = j0 + tx*8;
        const int tt = i + ((jb >> 7) << 8);
        float* dst = Mb + ((jb & 127) >> 2) * 2048 + tt * 4;
        float4 o0, o1;
        o0.x = 0.95f*acc[q][0] + ((i == jb+0) ? 0.05f : 0.f);
        o0.y = 0.95f*acc[q][1] + ((i == jb+1) ? 0.05f : 0.f);
        o0.z = 0.95f*acc[q][2] + ((i == jb+2) ? 0.05f : 0.f);
        o0.w = 0.95f*acc[q][3] + ((i == jb+3) ? 0.05f : 0.f);
        o1.x = 0.95f*acc[q][4] + ((i == jb+4) ? 0.05f : 0.f);
        o1.y = 0.95f*acc[q][5] + ((i == jb+5) ? 0.05f : 0.f);
        o1.z = 0.95f*acc[q][6] + ((i == jb+6) ? 0.05f : 0.f);
        o1.w = 0.95f*acc[q][7] + ((i == jb+7) ? 0.05f : 0.f);
        *(float4*)dst = o0;
        *(float4*)(dst + 2048) = o1;
    }
}

// Out[lm] = (G * diag(f(lam))) @ G^T   (fmode=1: rsqrt, fmode=0: log)
__global__ __launch_bounds__(256)
void tp_recon(const float* __restrict__ G, const float* __restrict__ lam,
              float* __restrict__ Out, int fmode)
{
    const int lm = blockIdx.y;
    const int i0 = (blockIdx.x >> 1) * 128, j0 = (blockIdx.x & 1) * 128;
    const float* Gb = G + (size_t)lm * 65536;
    float* Ob = Out + (size_t)lm * 65536;
    __shared__ float f[256];
    GEMM_PROLOGUE(Gb, Gb)
    {
        float l0 = fmaxf(lam[lm*256 + t], 1e-8f);
        f[t] = fmode ? rsqrtf(l0) : logf(l0);
    }
    for (int k0 = 0; k0 < 256; k0 += 16) {
        float4 a0 = *(const float4*)&Gb[(i0+li)*256 + k0 + lk];
        float4 a1 = *(const float4*)&Gb[(i0+li)*256 + k0 + lk + 4];
        float4 b0 = *(const float4*)&Gb[(j0+li)*256 + k0 + lk];
        float4 b1 = *(const float4*)&Gb[(j0+li)*256 + k0 + lk + 4];
        __syncthreads();
        As[lk+0][li]=a0.x*f[k0+lk+0]; As[lk+1][li]=a0.y*f[k0+lk+1];
        As[lk+2][li]=a0.z*f[k0+lk+2]; As[lk+3][li]=a0.w*f[k0+lk+3];
        As[lk+4][li]=a1.x*f[k0+lk+4]; As[lk+5][li]=a1.y*f[k0+lk+5];
        As[lk+6][li]=a1.z*f[k0+lk+6]; As[lk+7][li]=a1.w*f[k0+lk+7];
        Bs[lk+0][li]=b0.x; Bs[lk+1][li]=b0.y; Bs[lk+2][li]=b0.z; Bs[lk+3][li]=b0.w;
        Bs[lk+4][li]=b1.x; Bs[lk+5][li]=b1.y; Bs[lk+6][li]=b1.z; Bs[lk+7][li]=b1.w;
        __syncthreads();
        GEMM_INNER
    }
#pragma unroll
    for (int q = 0; q < 8; ++q) {
        float4 o0 = {acc[q][0],acc[q][1],acc[q][2],acc[q][3]};
        float4 o1 = {acc[q][4],acc[q][5],acc[q][6],acc[q][7]};
        *(float4*)&Ob[(i0+ty*8+q)*256 + j0 + tx*8]     = o0;
        *(float4*)&Ob[(i0+ty*8+q)*256 + j0 + tx*8 + 4] = o1;
    }
}

// ---------------------------------------------------------------------------
extern "C" void kernel_launch(void* const* d_in, const int* in_sizes, int n_in,
                              void* d_out, int out_size, void* d_ws, size_t ws_size,
                              hipStream_t stream)
{
    (void)in_sizes; (void)n_in; (void)out_size;
    const float* x = (const float*)d_in[0];     // (256,256,256)
    const float* w = (const float*)d_in[1];     // (4,256,256)
    float* out = (float*)d_out;                 // (256,4,256,256)
    float* ws  = (float*)d_ws;

    // ---- pick largest chunk size CS fitting ws_size (pure fn of ws_size:
    //      identical launch sequence every call -> graph-capture safe) ----
    int CS = 1024;
    while (CS > 4) {
        size_t need = 4ull * (524288ull + (size_t)CS * 99328ull);
        if (need <= ws_size) break;
        CS >>= 1;
    }

    float* S    = ws;                            // 4*65536
    float* Wp   = S    + (size_t)4*65536;        // 4*65536
    float* V    = Wp   + (size_t)4*65536;        // CS*32768
    float* tau  = V    + (size_t)CS*32768;       // CS*256
    float* dd   = tau  + (size_t)CS*256;
    float* ee   = dd   + (size_t)CS*256;
    float* lamb = ee   + (size_t)CS*256;
    float* EG   = lamb + (size_t)CS*256;         // CS*65536

    const int INVIT_LDS = 33280 * 4;   // 133120 B dynamic LDS
    hipFuncSetAttribute(reinterpret_cast<const void*>(tp_invit),
                        hipFuncAttributeMaxDynamicSharedMemorySize, INVIT_LDS);

    // ---- weight branch: S_c = (0.95 W + 0.05 I)^(-1/2), 4 matrices ----
    tp_regw<<<1024, 256, 0, stream>>>(w, Wp);
    tp_tridiag<<<4, 512, 0, stream>>>(Wp, V, tau, dd, ee);
    tp_bisect <<<4, 256, 0, stream>>>(dd, ee, lamb);
    tp_invit  <<<16, 64, INVIT_LDS, stream>>>(dd, ee, lamb, EG);
    tp_reorth <<<4, 256, 0, stream>>>(lamb, EG);
    tp_backxf <<<4, 512, 0, stream>>>(EG, V, tau);
    tp_recon  <<<dim3(4,4), 256, 0, stream>>>(EG, lamb, S, 1);

    // ---- main branch in chunks of CS matrices ----
    for (int mat0 = 0; mat0 < 1024; mat0 += CS) {
        float* outc = out + (size_t)mat0 * 65536;
        // congruence: M = 0.95 S x S + 0.05 I (M -> d_out chunk, perm layout)
        tp_gemm_xS<<<dim3(4,CS), 256, 0, stream>>>(x, S, EG, mat0);   // P = x S
        tp_gemm_SP<<<dim3(4,CS), 256, 0, stream>>>(S, EG, outc);      // M
        // eig + log reconstruction
        tp_tridiag<<<CS, 512, 0, stream>>>(outc, V, tau, dd, ee);
        tp_bisect <<<CS, 256, 0, stream>>>(dd, ee, lamb);
        tp_invit  <<<CS*4, 64, INVIT_LDS, stream>>>(dd, ee, lamb, EG);
        tp_reorth <<<CS, 256, 0, stream>>>(lamb, EG);
        tp_backxf <<<CS, 512, 0, stream>>>(EG, V, tau);
        tp_recon  <<<dim3(4,CS), 256, 0, stream>>>(EG, lamb, outc, 0);
    }
}

// Round 3
// 30002.826 us; speedup vs baseline: 1.5460x; 1.5460x over previous
//
#include <hip/hip_runtime.h>
#include <stdint.h>
#include <math.h>

// Problem: B=256, C=4, N=256, PSI=0.05
// out[b][c] = Q_log(0.95 * S_c x_b S_c + 0.05 I),  S_c = Q_rsqrt(0.95 W_c + 0.05 I)
// mat index = b*4 + c  (matches out[b][c] contiguity)
//
// Workspace layout (float offsets), runtime-chunked by CS matrices:
//   S    : 4*65536   S_c matrices
//   Wp   : 4*65536   W' (perm layout)
//   V    : CS*32768  packed Householder reflectors
//   tau  : CS*256
//   d    : CS*256    tridiag diagonal
//   e    : CS*256    tridiag subdiagonal
//   lam  : CS*256    eigenvalues (sorted)
//   EG   : CS*65536  P / E / G (phase-shared)
// bytes = 4*(524288 + CS*99328); CS=1024 -> ~409 MB, CS=256 -> ~103 MB.

__device__ __forceinline__ int tp_voff(int k) { return 255*k - (k*(k-1))/2; }

__device__ __forceinline__ float tp_hashf(uint32_t a) {
    a ^= a >> 16; a *= 0x7feb352du; a ^= a >> 15; a *= 0x846ca68bu; a ^= a >> 16;
    return (float)(a & 0xFFFFFFu) * (1.0f/16777216.0f) - 0.5f;
}

// permuted layout used as tridiag input: owner thread tt = i + (j>>7)*256,
// float offset = ((j&127)>>2)*2048 + tt*4 + (j&3). Bijective on 65536.

// ---------------------------------------------------------------------------
// W' = 0.95 W + 0.05 I  (write in permuted layout)
__global__ __launch_bounds__(256)
void tp_regw(const float* __restrict__ W, float* __restrict__ Wp)
{
    int g = blockIdx.x * 256 + threadIdx.x;          // 0 .. 262143
    int c = g >> 16, o = g & 65535;
    int jo = o >> 11, rrem = o & 2047, tt = rrem >> 2, ji = rrem & 3;
    int i = tt & 255;
    int j = ((tt >> 8) << 7) + (jo << 2) + ji;
    Wp[g] = 0.95f * W[c*65536 + i*256 + j] + ((i == j) ? 0.05f : 0.0f);
}

// ---------------------------------------------------------------------------
// Householder tridiagonalization. One matrix per 512-thread block; full
// symmetric matrix in registers: thread t owns row (t&255), cols (t>>8)*128..+127.
__global__ __launch_bounds__(512, 1)
void tp_tridiag(const float* __restrict__ Min, float* __restrict__ V,
                float* __restrict__ taug, float* __restrict__ dg,
                float* __restrict__ eg)
{
    const int mat = blockIdx.x;
    const int t   = threadIdx.x;
    const int row = t & 255;
    const int rh  = t >> 8;
    const int cb  = rh << 7;

    const float4* M4 = (const float4*)(Min + (size_t)mat * 65536);
    float* Vb = V + (size_t)mat * 32768;

    __shared__ __align__(16) float pivot[256];
    __shared__ __align__(16) float p2[2][256];
    __shared__ __align__(16) float vv[256];
    __shared__ __align__(16) float ww[256];

    float A[128];
#pragma unroll
    for (int jo = 0; jo < 32; ++jo) {
        float4 v4 = M4[jo * 512 + t];
        A[jo*4+0]=v4.x; A[jo*4+1]=v4.y; A[jo*4+2]=v4.z; A[jo*4+3]=v4.w;
    }
    if (t < 256) { vv[t] = 0.f; ww[t] = 0.f; }
    if (rh == 0) pivot[row] = A[0];            // column 0
    if (t == 0)  dg[mat*256] = A[0];
    __syncthreads();

    const int lane = t & 63;
    for (int k = 0; k < 254; ++k) {
        // ---- Householder scalars (redundant per wave; pivot = col k) ----
        float sig = 0.f;
        for (int i = k + 2 + lane; i < 256; i += 64) { float x = pivot[i]; sig = fmaf(x, x, sig); }
#pragma unroll
        for (int off = 32; off; off >>= 1) sig += __shfl_xor(sig, off);
        float alpha = pivot[k+1];
        float beta, tu, s;
        if (sig <= 1e-36f) { beta = alpha; tu = 0.f; s = 0.f; }
        else {
            beta = -copysignf(sqrtf(fmaf(alpha, alpha, sig)), alpha);
            tu   = (beta - alpha) / beta;
            s    = 1.f / (alpha - beta);
        }
        // ---- v (vv stays zero outside (k,255]) + packed V store ----
        if (t < 256) {
            int j = t;
            if (j == k) { vv[j] = 0.f; ww[j] = 0.f; }
            else if (j > k) {
                float val = (j == k+1) ? ((tu != 0.f) ? 1.f : 0.f) : pivot[j] * s;
                vv[j] = val;
                Vb[tp_voff(k) + (j - k - 1)] = val;
            }
        }
        if (t == 0) { taug[mat*256+k] = tu; eg[mat*256+k] = beta; }
        __syncthreads();
        // ---- p = A * v (no masking needed: vv is zero on dead cols) ----
        if (row > k) {
            float part = 0.f;
#pragma unroll
            for (int blk = 0; blk < 8; ++blk) {
                if (cb + blk*16 + 15 > k) {
#pragma unroll
                    for (int q = 0; q < 16; q += 4) {
                        float4 v4 = *(const float4*)&vv[cb + blk*16 + q];
                        part = fmaf(A[blk*16+q+0], v4.x, part);
                        part = fmaf(A[blk*16+q+1], v4.y, part);
                        part = fmaf(A[blk*16+q+2], v4.z, part);
                        part = fmaf(A[blk*16+q+3], v4.w, part);
                    }
                }
            }
            p2[rh][row] = part;
        }
        __syncthreads();
        // ---- w = tau*p - (tau^2 (v.p)/2) v ----
        float s2 = 0.f;
        for (int i = k + 1 + lane; i < 256; i += 64) s2 = fmaf(vv[i], p2[0][i] + p2[1][i], s2);
#pragma unroll
        for (int off = 32; off; off >>= 1) s2 += __shfl_xor(s2, off);
        float cc = 0.5f * tu * tu * s2;
        if (t < 256 && t > k) ww[t] = tu * (p2[0][t] + p2[1][t]) - cc * vv[t];
        __syncthreads();
        // ---- A -= v w^T + w v^T ; extract next pivot column k+1 ----
        if (row > k) {
            float vr = vv[row], wr = ww[row];
#pragma unroll
            for (int blk = 0; blk < 8; ++blk) {
                if (cb + blk*16 + 15 > k) {
#pragma unroll
                    for (int q = 0; q < 16; q += 4) {
                        float4 v4 = *(const float4*)&vv[cb + blk*16 + q];
                        float4 w4 = *(const float4*)&ww[cb + blk*16 + q];
                        float n0 = A[blk*16+q+0] - (vr*w4.x + wr*v4.x);
                        float n1 = A[blk*16+q+1] - (vr*w4.y + wr*v4.y);
                        float n2 = A[blk*16+q+2] - (vr*w4.z + wr*v4.z);
                        float n3 = A[blk*16+q+3] - (vr*w4.w + wr*v4.w);
                        A[blk*16+q+0] = n0; A[blk*16+q+1] = n1;
                        A[blk*16+q+2] = n2; A[blk*16+q+3] = n3;
                        const int jj = cb + blk*16 + q;      // wave-uniform
                        if (jj+0 == k+1) { pivot[row] = n0; if (row == k+1) dg[mat*256+k+1] = n0; }
                        if (jj+1 == k+1) { pivot[row] = n1; if (row == k+1) dg[mat*256+k+1] = n1; }
                        if (jj+2 == k+1) { pivot[row] = n2; if (row == k+1) dg[mat*256+k+1] = n2; }
                        if (jj+3 == k+1) { pivot[row] = n3; if (row == k+1) dg[mat*256+k+1] = n3; }
                    }
                }
            }
        }
        __syncthreads();
    }
    if (t == 0)   eg[mat*256+254] = pivot[255];   // A[255][254]
    if (t == 511) dg[mat*256+255] = A[127];       // A[255][255]
}

// ---------------------------------------------------------------------------
// All 256 eigenvalues by Sturm bisection; thread t -> t-th smallest (sorted).
__global__ __launch_bounds__(256)
void tp_bisect(const float* __restrict__ dg, const float* __restrict__ eg,
               float* __restrict__ lam)
{
    const int mat = blockIdx.x, t = threadIdx.x;
    __shared__ float d[256], e2[256];
    __shared__ float redmin[4], redmax[4];
    float dt = dg[mat*256+t];
    float et = (t < 255) ? eg[mat*256+t] : 0.f;
    d[t] = dt; e2[t] = et*et;
    float ep = (t > 0) ? eg[mat*256+t-1] : 0.f;
    float r = fabsf(et) + fabsf(ep);
    float lo = dt - r, hi = dt + r;
#pragma unroll
    for (int off = 32; off; off >>= 1) {
        lo = fminf(lo, __shfl_xor(lo, off));
        hi = fmaxf(hi, __shfl_xor(hi, off));
    }
    if ((t & 63) == 0) { redmin[t>>6] = lo; redmax[t>>6] = hi; }
    __syncthreads();
    float gl = fminf(fminf(redmin[0],redmin[1]), fminf(redmin[2],redmin[3]));
    float gu = fmaxf(fmaxf(redmax[0],redmax[1]), fmaxf(redmax[2],redmax[3]));
    float rng = gu - gl;
    gl -= 1e-6f*rng + 1e-30f; gu += 1e-6f*rng + 1e-30f;
    const float PIVB = 1e-30f;
    float l = gl, u = gu;
    for (int it = 0; it < 42; ++it) {
        float mid = 0.5f*(l+u);
        float q = d[0] - mid;
        if (fabsf(q) < PIVB) q = -PIVB;
        int cnt = (q < 0.f);
        for (int i = 1; i < 256; ++i) {
            q = d[i] - mid - e2[i-1]/q;
            if (fabsf(q) < PIVB) q = -PIVB;
            cnt += (q < 0.f);
        }
        if (cnt <= t) l = mid; else u = mid;
    }
    lam[mat*256+t] = 0.5f*(l+u);
}

// ---------------------------------------------------------------------------
// Inverse iteration on T (LDL^T solve), 64 eigenvectors per 64-thread block.
// Dynamic LDS: v[256][64], r[256][64], d[256], e[256] = 133120 bytes.
__global__ __launch_bounds__(64)
void tp_invit(const float* __restrict__ dg, const float* __restrict__ eg,
              const float* __restrict__ lam, float* __restrict__ E)
{
    extern __shared__ float ls[];
    float* vb = ls;              // [256][64]
    float* rb = ls + 16384;      // [256][64]
    float* d  = ls + 32768;      // 256
    float* e  = ls + 33024;      // 256 (e[255]=0)
    const int mat = blockIdx.x >> 2;
    const int t = threadIdx.x;
    const int vecid = ((blockIdx.x & 3) << 6) | t;
    for (int i = t; i < 256; i += 64) {
        d[i] = dg[mat*256+i];
        e[i] = (i < 255) ? eg[mat*256+i] : 0.f;
    }
    __syncthreads();
    float mx = 0.f;
    for (int i = t; i < 256; i += 64) mx = fmaxf(mx, fabsf(d[i]) + 2.f*fabsf(e[i]));
#pragma unroll
    for (int off = 32; off; off >>= 1) mx = fmaxf(mx, __shfl_xor(mx, off));
    const float piv = fmaxf(mx, 1e-10f) * 1e-8f;
    const float sigma = lam[mat*256 + vecid];
    const uint32_t sd = ((uint32_t)(mat*256 + vecid) << 9) + 12345u;
    for (int i = 0; i < 256; ++i) vb[i*64+t] = tp_hashf(sd + (uint32_t)i);

    for (int iter = 0; iter < 2; ++iter) {
        float rp, y;
        if (iter == 0) {
            float del = d[0] - sigma;
            if (fabsf(del) < piv) del = copysignf(piv, del);
            rp = 1.f / del; rb[t] = rp;
        } else rp = rb[t];
        y = vb[t];
        for (int i = 1; i < 256; ++i) {
            float ei = e[i-1];
            float lmul = ei * rp;
            float ri;
            if (iter == 0) {
                float dl = (d[i] - sigma) - lmul * ei;
                if (fabsf(dl) < piv) dl = copysignf(piv, dl);
                ri = 1.f / dl; rb[i*64+t] = ri;
            } else ri = rb[i*64+t];
            y = vb[i*64+t] - lmul * y;
            vb[i*64+t] = y;
            rp = ri;
        }
        float vn = vb[255*64+t] * rb[255*64+t];
        vb[255*64+t] = vn;
        float nrm = vn*vn;
        for (int i = 254; i >= 0; --i) {
            float vi = (vb[i*64+t] - e[i]*vn) * rb[i*64+t];
            vb[i*64+t] = vi; vn = vi;
            nrm = fmaf(vi, vi, nrm);
        }
        if (!(nrm > 1e-30f && nrm < 1e37f)) {     // breakdown / overflow guard
            for (int i = 0; i < 256; ++i) vb[i*64+t] = (i == vecid) ? 1.f : 0.f;
        } else {
            float sc = rsqrtf(nrm);
            for (int i = 0; i < 256; ++i) vb[i*64+t] *= sc;
        }
    }
    float* Eb = E + (size_t)mat*65536;
    for (int i = 0; i < 256; ++i) Eb[i*256 + vecid] = vb[i*64+t];   // E[comp][vec]
}

// ---------------------------------------------------------------------------
// LDS-tiled CGS2 re-orthogonalization inside eigenvalue clusters
// (gap < 6e-5 * range). One block per matrix. Each cluster is processed in
// tiles of RTK vectors held transposed in LDS; each tile is loaded/stored
// ONCE (vs per-pair strided global reads previously: 102 GB -> <1 GB fetch).
#define RTK     64
#define RPITCH  260            // multiple of 4 (float4-aligned rows), 260%32=4
#define REORTH_LDS (2*RTK*RPITCH*4)   // X + Y tiles = 133,120 B

__global__ __launch_bounds__(256)
void tp_reorth(const float* __restrict__ lam, float* __restrict__ E)
{
    extern __shared__ float rls[];
    float* X = rls;                    // [RTK][RPITCH] current tile (transposed)
    float* Y = rls + RTK*RPITCH;       // [RTK][RPITCH] previous tile
    __shared__ float l[256];
    __shared__ int ca[128], cb[128];   // cluster bounds (size>=2 clusters <=128)
    __shared__ int ncl;
    __shared__ float rs[RTK];
    __shared__ float pbuf[4][64];
    __shared__ float dbuf[64];
    __shared__ float nrmred[4];

    const int mat = blockIdx.x, t = threadIdx.x;
    const int lane = t & 63, wv = t >> 6;
    l[t] = lam[mat*256+t];
    __syncthreads();
    if (t == 0) {
        float thr = 6e-5f * (l[255] - l[0]) + 1e-30f;
        int n = 0, a = 0;
        for (int j = 1; j <= 256; ++j) {
            bool brk = (j == 256) || (l[j] - l[j-1] >= thr);
            if (brk) {
                if (j - a >= 2 && n < 128) { ca[n] = a; cb[n] = j; ++n; }
                a = j;
            }
        }
        ncl = n;
    }
    __syncthreads();
    const int nc = ncl;
    float* Eb = E + (size_t)mat*65536;

    for (int cidx = 0; cidx < nc; ++cidx) {
        const int a = ca[cidx], b = cb[cidx], k = b - a;
        const int ntile = (k + RTK - 1) / RTK;
        for (int m = 0; m < ntile; ++m) {
            const int ta = a + m*RTK;
            const int kt = min(RTK, b - ta);
            // ---- load tile -> X transposed (coalesced: 64 lanes over vecs) --
            for (int c = wv; c < 256; c += 4)
                if (lane < kt) X[lane*RPITCH + c] = Eb[c*256 + ta + lane];
            __syncthreads();
            for (int sweep = 0; sweep < 2; ++sweep) {
                // ---- project out previous (already-final) tiles ----
                for (int p = 0; p < m; ++p) {
                    const int pa = a + p*RTK;
                    for (int c = wv; c < 256; c += 4)
                        Y[lane*RPITCH + c] = Eb[c*256 + pa + lane];
                    __syncthreads();
                    for (int i = 0; i < RTK; ++i) {
                        float part = 0.f;
                        if (lane < kt) {
                            for (int cc = 0; cc < 64; ++cc) {
                                int c = wv*64 + cc;
                                part = fmaf(Y[i*RPITCH + c], X[lane*RPITCH + c], part);
                            }
                        }
                        pbuf[wv][lane] = part;
                        __syncthreads();
                        if (t < 64) dbuf[t] = pbuf[0][t]+pbuf[1][t]+pbuf[2][t]+pbuf[3][t];
                        __syncthreads();
                        if (lane < kt) {
                            float dl = dbuf[lane];
                            for (int cc = 0; cc < 64; ++cc) {
                                int c = wv*64 + cc;
                                X[lane*RPITCH + c] -= dl * Y[i*RPITCH + c];
                            }
                        }
                        __syncthreads();
                    }
                }
                // ---- internal CGS sweep (wave-parallel dots, no per-dot barrier) ----
                for (int j = 0; j < kt; ++j) {
                    for (int i = wv; i < j; i += 4) {
                        float4 xa = *(const float4*)&X[i*RPITCH + 4*lane];
                        float4 xb = *(const float4*)&X[j*RPITCH + 4*lane];
                        float pp = xa.x*xb.x + xa.y*xb.y + xa.z*xb.z + xa.w*xb.w;
#pragma unroll
                        for (int off = 32; off; off >>= 1) pp += __shfl_xor(pp, off);
                        if (lane == 0) rs[i] = pp;
                    }
                    __syncthreads();
                    float xc = X[j*RPITCH + t];
                    for (int i = 0; i < j; ++i) xc -= rs[i] * X[i*RPITCH + t];
                    float nn = xc*xc;
#pragma unroll
                    for (int off = 32; off; off >>= 1) nn += __shfl_xor(nn, off);
                    if (lane == 0) nrmred[wv] = nn;
                    __syncthreads();
                    float nrm = nrmred[0]+nrmred[1]+nrmred[2]+nrmred[3];
                    float sc = (nrm > 1e-30f) ? rsqrtf(nrm) : 1.f;
                    X[j*RPITCH + t] = xc * sc;
                    __syncthreads();
                }
            }
            // ---- store tile back ----
            for (int c = wv; c < 256; c += 4)
                if (lane < kt) Eb[c*256 + ta + lane] = X[lane*RPITCH + c];
            __syncthreads();
        }
    }
}

// ---------------------------------------------------------------------------
// Back-transform: G = H_0 ... H_253 E (apply reflectors in reverse order).
// Thread t owns column (t&255), rows (t>>8)*128..+127 in registers.
__global__ __launch_bounds__(512, 1)
void tp_backxf(float* __restrict__ E, const float* __restrict__ V,
               const float* __restrict__ taug)
{
    const int mat = blockIdx.x, t = threadIdx.x;
    const int j = t & 255, rh = t >> 8;
    float* Eb = E + (size_t)mat*65536;
    const float* Vb = V + (size_t)mat*32768;
    const float* taub = taug + mat*256;
    __shared__ __align__(16) float vbuf[2][256];
    __shared__ float part[2][256];
    __shared__ float taush[2];
    float Er[128];
#pragma unroll
    for (int r = 0; r < 128; ++r) Er[r] = Eb[(rh*128 + r)*256 + j];
    ((float*)vbuf)[t & 511] = 0.f;                 // zero both buffers (512 floats)
    __syncthreads();
    if (t < 2) vbuf[0][254 + t] = Vb[tp_voff(253) + t];
    if (t == 0) taush[0] = taub[253];
    for (int k = 253; k >= 0; --k) {
        const int cur = (253 - k) & 1;
        __syncthreads();                           // vbuf[cur]/taush[cur] ready
        const float tu = taush[cur];
        float p = 0.f;
#pragma unroll
        for (int blk = 0; blk < 8; ++blk) {
            const int rbase = rh*128 + blk*16;
            if (rbase + 15 > k) {                  // rows <= k read zeros anyway
#pragma unroll
                for (int q = 0; q < 16; q += 4) {
                    float4 v4 = *(const float4*)&vbuf[cur][rbase + q];
                    p = fmaf(Er[blk*16+q+0], v4.x, p);
                    p = fmaf(Er[blk*16+q+1], v4.y, p);
                    p = fmaf(Er[blk*16+q+2], v4.z, p);
                    p = fmaf(Er[blk*16+q+3], v4.w, p);
                }
            }
        }
        part[rh][j] = p;
        __syncthreads();
        const float sj = (part[0][j] + part[1][j]) * tu;
        if (k > 0) {                               // prefetch next reflector
            const int kn = k - 1, len = 255 - kn, vo = tp_voff(kn);
            for (int idx = t; idx < len; idx += 512)
                vbuf[cur^1][kn+1+idx] = Vb[vo + idx];
            if (t == 0) taush[cur^1] = taub[kn];
        }
#pragma unroll
        for (int blk = 0; blk < 8; ++blk) {
            const int rbase = rh*128 + blk*16;
            if (rbase + 15 > k) {
#pragma unroll
                for (int q = 0; q < 16; q += 4) {
                    float4 v4 = *(const float4*)&vbuf[cur][rbase + q];
                    Er[blk*16+q+0] = fmaf(-sj, v4.x, Er[blk*16+q+0]);
                    Er[blk*16+q+1] = fmaf(-sj, v4.y, Er[blk*16+q+1]);
                    Er[blk*16+q+2] = fmaf(-sj, v4.z, Er[blk*16+q+2]);
                    Er[blk*16+q+3] = fmaf(-sj, v4.w, Er[blk*16+q+3]);
                }
            }
        }
    }
#pragma unroll
    for (int r = 0; r < 128; ++r) Eb[(rh*128 + r)*256 + j] = Er[r];
}

// ---------------------------------------------------------------------------
// fp32 128x128-tile GEMMs (256 thr, 8x8 micro-tile, K-step 16)
#define GEMM_PROLOGUE(Aptr, Bptr)                                              \
    __shared__ __align__(16) float As[16][132];                                \
    __shared__ __align__(16) float Bs[16][132];                                \
    const int t = threadIdx.x, tx = t & 15, ty = t >> 4;                       \
    const int li = t >> 1, lk = (t & 1) * 8;                                   \
    const int bk = t >> 4, bj = (t & 15) * 8;                                  \
    float acc[8][8];                                                           \
    _Pragma("unroll") for (int q = 0; q < 8; ++q)                              \
    _Pragma("unroll") for (int r2 = 0; r2 < 8; ++r2) acc[q][r2] = 0.f;

#define GEMM_INNER                                                             \
    _Pragma("unroll")                                                          \
    for (int kk = 0; kk < 16; ++kk) {                                          \
        float4 av0 = *(const float4*)&As[kk][ty*8];                            \
        float4 av1 = *(const float4*)&As[kk][ty*8+4];                          \
        float4 bv0 = *(const float4*)&Bs[kk][tx*8];                            \
        float4 bv1 = *(const float4*)&Bs[kk][tx*8+4];                          \
        float av[8] = {av0.x,av0.y,av0.z,av0.w,av1.x,av1.y,av1.z,av1.w};       \
        float bw[8] = {bv0.x,bv0.y,bv0.z,bv0.w,bv1.x,bv1.y,bv1.z,bv1.w};       \
        _Pragma("unroll") for (int q = 0; q < 8; ++q)                          \
        _Pragma("unroll") for (int r2 = 0; r2 < 8; ++r2)                       \
            acc[q][r2] = fmaf(av[q], bw[r2], acc[q][r2]);                      \
    }

// P[lm] = x_b @ S_c,  gm = mat0 + lm
__global__ __launch_bounds__(256)
void tp_gemm_xS(const float* __restrict__ X, const float* __restrict__ S,
                float* __restrict__ P, int mat0)
{
    const int lm = blockIdx.y, gm = mat0 + lm, b = gm >> 2, c = gm & 3;
    const int i0 = (blockIdx.x >> 1) * 128, j0 = (blockIdx.x & 1) * 128;
    const float* Ag = X + (size_t)b * 65536;
    const float* Bg = S + (size_t)c * 65536;
    float* Cg = P + (size_t)lm * 65536;
    GEMM_PROLOGUE(Ag, Bg)
    for (int k0 = 0; k0 < 256; k0 += 16) {
        float4 a0 = *(const float4*)&Ag[(i0+li)*256 + k0 + lk];
        float4 a1 = *(const float4*)&Ag[(i0+li)*256 + k0 + lk + 4];
        float4 b0 = *(const float4*)&Bg[(k0+bk)*256 + j0 + bj];
        float4 b1 = *(const float4*)&Bg[(k0+bk)*256 + j0 + bj + 4];
        __syncthreads();
        As[lk+0][li]=a0.x; As[lk+1][li]=a0.y; As[lk+2][li]=a0.z; As[lk+3][li]=a0.w;
        As[lk+4][li]=a1.x; As[lk+5][li]=a1.y; As[lk+6][li]=a1.z; As[lk+7][li]=a1.w;
        *(float4*)&Bs[bk][bj] = b0;  *(float4*)&Bs[bk][bj+4] = b1;
        __syncthreads();
        GEMM_INNER
    }
#pragma unroll
    for (int q = 0; q < 8; ++q) {
        float4 o0 = {acc[q][0],acc[q][1],acc[q][2],acc[q][3]};
        float4 o1 = {acc[q][4],acc[q][5],acc[q][6],acc[q][7]};
        *(float4*)&Cg[(i0+ty*8+q)*256 + j0 + tx*8]     = o0;
        *(float4*)&Cg[(i0+ty*8+q)*256 + j0 + tx*8 + 4] = o1;
    }
}

// M[lm] = 0.95 * S_c @ P[lm] + 0.05 I -> permuted layout (Mout pre-offset;
// requires mat0 % 4 == 0 so c = lm & 3)
__global__ __launch_bounds__(256)
void tp_gemm_SP(const float* __restrict__ S, const float* __restrict__ P,
                float* __restrict__ Mout)
{
    const int lm = blockIdx.y, c = lm & 3;
    const int i0 = (blockIdx.x >> 1) * 128, j0 = (blockIdx.x & 1) * 128;
    const float* Ag = S + (size_t)c * 65536;
    const float* Bg = P + (size_t)lm * 65536;
    float* Mb = Mout + (size_t)lm * 65536;
    GEMM_PROLOGUE(Ag, Bg)
    for (int k0 = 0; k0 < 256; k0 += 16) {
        float4 a0 = *(const float4*)&Ag[(i0+li)*256 + k0 + lk];
        float4 a1 = *(const float4*)&Ag[(i0+li)*256 + k0 + lk + 4];
        float4 b0 = *(const float4*)&Bg[(k0+bk)*256 + j0 + bj];
        float4 b1 = *(const float4*)&Bg[(k0+bk)*256 + j0 + bj + 4];
        __syncthreads();
        As[lk+0][li]=a0.x; As[lk+1][li]=a0.y; As[lk+2][li]=a0.z; As[lk+3][li]=a0.w;
        As[lk+4][li]=a1.x; As[lk+5][li]=a1.y; As[lk+6][li]=a1.z; As[lk+7][li]=a1.w;
        *(float4*)&Bs[bk][bj] = b0;  *(float4*)&Bs[bk][bj+4] = b1;
        __syncthreads();
        GEMM_INNER
    }
#pragma unroll
    for (int q = 0; q < 8; ++q) {
        const int i = i0 + ty*8 + q;
        const int jb = j0 + tx*8;
        const int tt = i + ((jb >> 7) << 8);
        float* dst = Mb + ((jb & 127) >> 2) * 2048 + tt * 4;
        float4 o0, o1;
        o0.x = 0.95f*acc[q][0] + ((i == jb+0) ? 0.05f : 0.f);
        o0.y = 0.95f*acc[q][1] + ((i == jb+1) ? 0.05f : 0.f);
        o0.z = 0.95f*acc[q][2] + ((i == jb+2) ? 0.05f : 0.f);
        o0.w = 0.95f*acc[q][3] + ((i == jb+3) ? 0.05f : 0.f);
        o1.x = 0.95f*acc[q][4] + ((i == jb+4) ? 0.05f : 0.f);
        o1.y = 0.95f*acc[q][5] + ((i == jb+5) ? 0.05f : 0.f);
        o1.z = 0.95f*acc[q][6] + ((i == jb+6) ? 0.05f : 0.f);
        o1.w = 0.95f*acc[q][7] + ((i == jb+7) ? 0.05f : 0.f);
        *(float4*)dst = o0;
        *(float4*)(dst + 2048) = o1;
    }
}

// Out[lm] = (G * diag(f(lam))) @ G^T   (fmode=1: rsqrt, fmode=0: log)
__global__ __launch_bounds__(256)
void tp_recon(const float* __restrict__ G, const float* __restrict__ lam,
              float* __restrict__ Out, int fmode)
{
    const int lm = blockIdx.y;
    const int i0 = (blockIdx.x >> 1) * 128, j0 = (blockIdx.x & 1) * 128;
    const float* Gb = G + (size_t)lm * 65536;
    float* Ob = Out + (size_t)lm * 65536;
    __shared__ float f[256];
    GEMM_PROLOGUE(Gb, Gb)
    {
        float l0 = fmaxf(lam[lm*256 + t], 1e-8f);
        f[t] = fmode ? rsqrtf(l0) : logf(l0);
    }
    for (int k0 = 0; k0 < 256; k0 += 16) {
        float4 a0 = *(const float4*)&Gb[(i0+li)*256 + k0 + lk];
        float4 a1 = *(const float4*)&Gb[(i0+li)*256 + k0 + lk + 4];
        float4 b0 = *(const float4*)&Gb[(j0+li)*256 + k0 + lk];
        float4 b1 = *(const float4*)&Gb[(j0+li)*256 + k0 + lk + 4];
        __syncthreads();
        As[lk+0][li]=a0.x*f[k0+lk+0]; As[lk+1][li]=a0.y*f[k0+lk+1];
        As[lk+2][li]=a0.z*f[k0+lk+2]; As[lk+3][li]=a0.w*f[k0+lk+3];
        As[lk+4][li]=a1.x*f[k0+lk+4]; As[lk+5][li]=a1.y*f[k0+lk+5];
        As[lk+6][li]=a1.z*f[k0+lk+6]; As[lk+7][li]=a1.w*f[k0+lk+7];
        Bs[lk+0][li]=b0.x; Bs[lk+1][li]=b0.y; Bs[lk+2][li]=b0.z; Bs[lk+3][li]=b0.w;
        Bs[lk+4][li]=b1.x; Bs[lk+5][li]=b1.y; Bs[lk+6][li]=b1.z; Bs[lk+7][li]=b1.w;
        __syncthreads();
        GEMM_INNER
    }
#pragma unroll
    for (int q = 0; q < 8; ++q) {
        float4 o0 = {acc[q][0],acc[q][1],acc[q][2],acc[q][3]};
        float4 o1 = {acc[q][4],acc[q][5],acc[q][6],acc[q][7]};
        *(float4*)&Ob[(i0+ty*8+q)*256 + j0 + tx*8]     = o0;
        *(float4*)&Ob[(i0+ty*8+q)*256 + j0 + tx*8 + 4] = o1;
    }
}

// ---------------------------------------------------------------------------
extern "C" void kernel_launch(void* const* d_in, const int* in_sizes, int n_in,
                              void* d_out, int out_size, void* d_ws, size_t ws_size,
                              hipStream_t stream)
{
    (void)in_sizes; (void)n_in; (void)out_size;
    const float* x = (const float*)d_in[0];     // (256,256,256)
    const float* w = (const float*)d_in[1];     // (4,256,256)
    float* out = (float*)d_out;                 // (256,4,256,256)
    float* ws  = (float*)d_ws;

    // ---- pick largest chunk size CS fitting ws_size (pure fn of ws_size:
    //      identical launch sequence every call -> graph-capture safe) ----
    int CS = 1024;
    while (CS > 4) {
        size_t need = 4ull * (524288ull + (size_t)CS * 99328ull);
        if (need <= ws_size) break;
        CS >>= 1;
    }

    float* S    = ws;                            // 4*65536
    float* Wp   = S    + (size_t)4*65536;        // 4*65536
    float* V    = Wp   + (size_t)4*65536;        // CS*32768
    float* tau  = V    + (size_t)CS*32768;       // CS*256
    float* dd   = tau  + (size_t)CS*256;
    float* ee   = dd   + (size_t)CS*256;
    float* lamb = ee   + (size_t)CS*256;
    float* EG   = lamb + (size_t)CS*256;         // CS*65536

    const int INVIT_LDS = 33280 * 4;   // 133120 B dynamic LDS
    hipFuncSetAttribute(reinterpret_cast<const void*>(tp_invit),
                        hipFuncAttributeMaxDynamicSharedMemorySize, INVIT_LDS);
    hipFuncSetAttribute(reinterpret_cast<const void*>(tp_reorth),
                        hipFuncAttributeMaxDynamicSharedMemorySize, REORTH_LDS);

    // ---- weight branch: S_c = (0.95 W + 0.05 I)^(-1/2), 4 matrices ----
    tp_regw<<<1024, 256, 0, stream>>>(w, Wp);
    tp_tridiag<<<4, 512, 0, stream>>>(Wp, V, tau, dd, ee);
    tp_bisect <<<4, 256, 0, stream>>>(dd, ee, lamb);
    tp_invit  <<<16, 64, INVIT_LDS, stream>>>(dd, ee, lamb, EG);
    tp_reorth <<<4, 256, REORTH_LDS, stream>>>(lamb, EG);
    tp_backxf <<<4, 512, 0, stream>>>(EG, V, tau);
    tp_recon  <<<dim3(4,4), 256, 0, stream>>>(EG, lamb, S, 1);

    // ---- main branch in chunks of CS matrices ----
    for (int mat0 = 0; mat0 < 1024; mat0 += CS) {
        float* outc = out + (size_t)mat0 * 65536;
        // congruence: M = 0.95 S x S + 0.05 I (M -> d_out chunk, perm layout)
        tp_gemm_xS<<<dim3(4,CS), 256, 0, stream>>>(x, S, EG, mat0);   // P = x S
        tp_gemm_SP<<<dim3(4,CS), 256, 0, stream>>>(S, EG, outc);      // M
        // eig + log reconstruction
        tp_tridiag<<<CS, 512, 0, stream>>>(outc, V, tau, dd, ee);
        tp_bisect <<<CS, 256, 0, stream>>>(dd, ee, lamb);
        tp_invit  <<<CS*4, 64, INVIT_LDS, stream>>>(dd, ee, lamb, EG);
        tp_reorth <<<CS, 256, REORTH_LDS, stream>>>(lamb, EG);
        tp_backxf <<<CS, 512, 0, stream>>>(EG, V, tau);
        tp_recon  <<<dim3(4,CS), 256, 0, stream>>>(EG, lamb, outc, 0);
    }
}

// Round 4
// 19256.943 us; speedup vs baseline: 2.4087x; 1.5580x over previous
//
#include <hip/hip_runtime.h>
#include <stdint.h>
#include <math.h>

// Problem: B=256, C=4, N=256, PSI=0.05
// out[b][c] = Q_log(0.95 * S_c x_b S_c + 0.05 I),  S_c = Q_rsqrt(0.95 W_c + 0.05 I)
// mat index = b*4 + c  (matches out[b][c] contiguity)
//
// Workspace layout (float offsets), runtime-chunked by CS matrices:
//   S    : 4*65536   S_c matrices
//   Wp   : 4*65536   W' (perm layout)
//   V    : CS*32768  packed Householder reflectors
//   tau  : CS*256
//   d    : CS*256    tridiag diagonal
//   e    : CS*256    tridiag subdiagonal
//   lam  : CS*256    eigenvalues (sorted)
//   EG   : CS*65536  P / E / G (phase-shared)
// bytes = 4*(524288 + CS*99328); CS=1024 -> ~409 MB, CS=256 -> ~103 MB.
// Orthogonalization C-scratch uses the d_out chunk (dead between tridiag and recon).

__device__ __forceinline__ int tp_voff(int k) { return 255*k - (k*(k-1))/2; }

__device__ __forceinline__ float tp_hashf(uint32_t a) {
    a ^= a >> 16; a *= 0x7feb352du; a ^= a >> 15; a *= 0x846ca68bu; a ^= a >> 16;
    return (float)(a & 0xFFFFFFu) * (1.0f/16777216.0f) - 0.5f;
}

// permuted layout used as tridiag input: owner thread tt = i + (j>>7)*256,
// float offset = ((j&127)>>2)*2048 + tt*4 + (j&3). Bijective on 65536.

// ---------------------------------------------------------------------------
// W' = 0.95 W + 0.05 I  (write in permuted layout)
__global__ __launch_bounds__(256)
void tp_regw(const float* __restrict__ W, float* __restrict__ Wp)
{
    int g = blockIdx.x * 256 + threadIdx.x;          // 0 .. 262143
    int c = g >> 16, o = g & 65535;
    int jo = o >> 11, rrem = o & 2047, tt = rrem >> 2, ji = rrem & 3;
    int i = tt & 255;
    int j = ((tt >> 8) << 7) + (jo << 2) + ji;
    Wp[g] = 0.95f * W[c*65536 + i*256 + j] + ((i == j) ? 0.05f : 0.0f);
}

// ---------------------------------------------------------------------------
// Householder tridiagonalization. One matrix per 512-thread block; full
// symmetric matrix in registers: thread t owns row (t&255), cols (t>>8)*128..+127.
__global__ __launch_bounds__(512, 1)
void tp_tridiag(const float* __restrict__ Min, float* __restrict__ V,
                float* __restrict__ taug, float* __restrict__ dg,
                float* __restrict__ eg)
{
    const int mat = blockIdx.x;
    const int t   = threadIdx.x;
    const int row = t & 255;
    const int rh  = t >> 8;
    const int cb  = rh << 7;

    const float4* M4 = (const float4*)(Min + (size_t)mat * 65536);
    float* Vb = V + (size_t)mat * 32768;

    __shared__ __align__(16) float pivot[256];
    __shared__ __align__(16) float p2[2][256];
    __shared__ __align__(16) float vv[256];
    __shared__ __align__(16) float ww[256];

    float A[128];
#pragma unroll
    for (int jo = 0; jo < 32; ++jo) {
        float4 v4 = M4[jo * 512 + t];
        A[jo*4+0]=v4.x; A[jo*4+1]=v4.y; A[jo*4+2]=v4.z; A[jo*4+3]=v4.w;
    }
    if (t < 256) { vv[t] = 0.f; ww[t] = 0.f; }
    if (rh == 0) pivot[row] = A[0];            // column 0
    if (t == 0)  dg[mat*256] = A[0];
    __syncthreads();

    const int lane = t & 63;
    for (int k = 0; k < 254; ++k) {
        // ---- Householder scalars (redundant per wave; pivot = col k) ----
        float sig = 0.f;
        for (int i = k + 2 + lane; i < 256; i += 64) { float x = pivot[i]; sig = fmaf(x, x, sig); }
#pragma unroll
        for (int off = 32; off; off >>= 1) sig += __shfl_xor(sig, off);
        float alpha = pivot[k+1];
        float beta, tu, s;
        if (sig <= 1e-36f) { beta = alpha; tu = 0.f; s = 0.f; }
        else {
            beta = -copysignf(sqrtf(fmaf(alpha, alpha, sig)), alpha);
            tu   = (beta - alpha) / beta;
            s    = 1.f / (alpha - beta);
        }
        // ---- v (vv stays zero outside (k,255]) + packed V store ----
        if (t < 256) {
            int j = t;
            if (j == k) { vv[j] = 0.f; ww[j] = 0.f; }
            else if (j > k) {
                float val = (j == k+1) ? ((tu != 0.f) ? 1.f : 0.f) : pivot[j] * s;
                vv[j] = val;
                Vb[tp_voff(k) + (j - k - 1)] = val;
            }
        }
        if (t == 0) { taug[mat*256+k] = tu; eg[mat*256+k] = beta; }
        __syncthreads();
        // ---- p = A * v (no masking needed: vv is zero on dead cols) ----
        if (row > k) {
            float part = 0.f;
#pragma unroll
            for (int blk = 0; blk < 8; ++blk) {
                if (cb + blk*16 + 15 > k) {
#pragma unroll
                    for (int q = 0; q < 16; q += 4) {
                        float4 v4 = *(const float4*)&vv[cb + blk*16 + q];
                        part = fmaf(A[blk*16+q+0], v4.x, part);
                        part = fmaf(A[blk*16+q+1], v4.y, part);
                        part = fmaf(A[blk*16+q+2], v4.z, part);
                        part = fmaf(A[blk*16+q+3], v4.w, part);
                    }
                }
            }
            p2[rh][row] = part;
        }
        __syncthreads();
        // ---- w = tau*p - (tau^2 (v.p)/2) v ----
        float s2 = 0.f;
        for (int i = k + 1 + lane; i < 256; i += 64) s2 = fmaf(vv[i], p2[0][i] + p2[1][i], s2);
#pragma unroll
        for (int off = 32; off; off >>= 1) s2 += __shfl_xor(s2, off);
        float cc = 0.5f * tu * tu * s2;
        if (t < 256 && t > k) ww[t] = tu * (p2[0][t] + p2[1][t]) - cc * vv[t];
        __syncthreads();
        // ---- A -= v w^T + w v^T ; extract next pivot column k+1 ----
        if (row > k) {
            float vr = vv[row], wr = ww[row];
#pragma unroll
            for (int blk = 0; blk < 8; ++blk) {
                if (cb + blk*16 + 15 > k) {
#pragma unroll
                    for (int q = 0; q < 16; q += 4) {
                        float4 v4 = *(const float4*)&vv[cb + blk*16 + q];
                        float4 w4 = *(const float4*)&ww[cb + blk*16 + q];
                        float n0 = A[blk*16+q+0] - (vr*w4.x + wr*v4.x);
                        float n1 = A[blk*16+q+1] - (vr*w4.y + wr*v4.y);
                        float n2 = A[blk*16+q+2] - (vr*w4.z + wr*v4.z);
                        float n3 = A[blk*16+q+3] - (vr*w4.w + wr*v4.w);
                        A[blk*16+q+0] = n0; A[blk*16+q+1] = n1;
                        A[blk*16+q+2] = n2; A[blk*16+q+3] = n3;
                        const int jj = cb + blk*16 + q;      // wave-uniform
                        if (jj+0 == k+1) { pivot[row] = n0; if (row == k+1) dg[mat*256+k+1] = n0; }
                        if (jj+1 == k+1) { pivot[row] = n1; if (row == k+1) dg[mat*256+k+1] = n1; }
                        if (jj+2 == k+1) { pivot[row] = n2; if (row == k+1) dg[mat*256+k+1] = n2; }
                        if (jj+3 == k+1) { pivot[row] = n3; if (row == k+1) dg[mat*256+k+1] = n3; }
                    }
                }
            }
        }
        __syncthreads();
    }
    if (t == 0)   eg[mat*256+254] = pivot[255];   // A[255][254]
    if (t == 511) dg[mat*256+255] = A[127];       // A[255][255]
}

// ---------------------------------------------------------------------------
// All 256 eigenvalues by Sturm bisection; thread t -> t-th smallest (sorted).
__global__ __launch_bounds__(256)
void tp_bisect(const float* __restrict__ dg, const float* __restrict__ eg,
               float* __restrict__ lam)
{
    const int mat = blockIdx.x, t = threadIdx.x;
    __shared__ float d[256], e2[256];
    __shared__ float redmin[4], redmax[4];
    float dt = dg[mat*256+t];
    float et = (t < 255) ? eg[mat*256+t] : 0.f;
    d[t] = dt; e2[t] = et*et;
    float ep = (t > 0) ? eg[mat*256+t-1] : 0.f;
    float r = fabsf(et) + fabsf(ep);
    float lo = dt - r, hi = dt + r;
#pragma unroll
    for (int off = 32; off; off >>= 1) {
        lo = fminf(lo, __shfl_xor(lo, off));
        hi = fmaxf(hi, __shfl_xor(hi, off));
    }
    if ((t & 63) == 0) { redmin[t>>6] = lo; redmax[t>>6] = hi; }
    __syncthreads();
    float gl = fminf(fminf(redmin[0],redmin[1]), fminf(redmin[2],redmin[3]));
    float gu = fmaxf(fmaxf(redmax[0],redmax[1]), fmaxf(redmax[2],redmax[3]));
    float rng = gu - gl;
    gl -= 1e-6f*rng + 1e-30f; gu += 1e-6f*rng + 1e-30f;
    const float PIVB = 1e-30f;
    float l = gl, u = gu;
    for (int it = 0; it < 42; ++it) {
        float mid = 0.5f*(l+u);
        float q = d[0] - mid;
        if (fabsf(q) < PIVB) q = -PIVB;
        int cnt = (q < 0.f);
        for (int i = 1; i < 256; ++i) {
            q = d[i] - mid - e2[i-1]/q;
            if (fabsf(q) < PIVB) q = -PIVB;
            cnt += (q < 0.f);
        }
        if (cnt <= t) l = mid; else u = mid;
    }
    lam[mat*256+t] = 0.5f*(l+u);
}

// ---------------------------------------------------------------------------
// Inverse iteration on T (LDL^T solve), 64 eigenvectors per 64-thread block.
// Dynamic LDS: v[256][64], r[256][64], d[256], e[256] = 133120 bytes.
__global__ __launch_bounds__(64)
void tp_invit(const float* __restrict__ dg, const float* __restrict__ eg,
              const float* __restrict__ lam, float* __restrict__ E)
{
    extern __shared__ float ls[];
    float* vb = ls;              // [256][64]
    float* rb = ls + 16384;      // [256][64]
    float* d  = ls + 32768;      // 256
    float* e  = ls + 33024;      // 256 (e[255]=0)
    const int mat = blockIdx.x >> 2;
    const int t = threadIdx.x;
    const int vecid = ((blockIdx.x & 3) << 6) | t;
    for (int i = t; i < 256; i += 64) {
        d[i] = dg[mat*256+i];
        e[i] = (i < 255) ? eg[mat*256+i] : 0.f;
    }
    __syncthreads();
    float mx = 0.f;
    for (int i = t; i < 256; i += 64) mx = fmaxf(mx, fabsf(d[i]) + 2.f*fabsf(e[i]));
#pragma unroll
    for (int off = 32; off; off >>= 1) mx = fmaxf(mx, __shfl_xor(mx, off));
    const float piv = fmaxf(mx, 1e-10f) * 1e-8f;
    const float sigma = lam[mat*256 + vecid];
    const uint32_t sd = ((uint32_t)(mat*256 + vecid) << 9) + 12345u;
    for (int i = 0; i < 256; ++i) vb[i*64+t] = tp_hashf(sd + (uint32_t)i);

    for (int iter = 0; iter < 2; ++iter) {
        float rp, y;
        if (iter == 0) {
            float del = d[0] - sigma;
            if (fabsf(del) < piv) del = copysignf(piv, del);
            rp = 1.f / del; rb[t] = rp;
        } else rp = rb[t];
        y = vb[t];
        for (int i = 1; i < 256; ++i) {
            float ei = e[i-1];
            float lmul = ei * rp;
            float ri;
            if (iter == 0) {
                float dl = (d[i] - sigma) - lmul * ei;
                if (fabsf(dl) < piv) dl = copysignf(piv, dl);
                ri = 1.f / dl; rb[i*64+t] = ri;
            } else ri = rb[i*64+t];
            y = vb[i*64+t] - lmul * y;
            vb[i*64+t] = y;
            rp = ri;
        }
        float vn = vb[255*64+t] * rb[255*64+t];
        vb[255*64+t] = vn;
        float nrm = vn*vn;
        for (int i = 254; i >= 0; --i) {
            float vi = (vb[i*64+t] - e[i]*vn) * rb[i*64+t];
            vb[i*64+t] = vi; vn = vi;
            nrm = fmaf(vi, vi, nrm);
        }
        if (!(nrm > 1e-30f && nrm < 1e37f)) {     // breakdown / overflow guard
            for (int i = 0; i < 256; ++i) vb[i*64+t] = (i == vecid) ? 1.f : 0.f;
        } else {
            float sc = rsqrtf(nrm);
            for (int i = 0; i < 256; ++i) vb[i*64+t] *= sc;
        }
    }
    float* Eb = E + (size_t)mat*65536;
    for (int i = 0; i < 256; ++i) Eb[i*256 + vecid] = vb[i*64+t];   // E[comp][vec]
}

// ---------------------------------------------------------------------------
// Full-basis blocked orthogonalization (replaces cluster-MGS):
// for strip s (64 cols): project out strips <s (one classical block sweep,
// two GEMMs), then in-strip shifted CholeskyQR2. Data-independent shapes.

// C = Q^T X_s: Q = E[:,0:js], X_s = E[:,js:js+64]. C scratch stride 65536/mat.
__global__ __launch_bounds__(256)
void tp_gsC(const float* __restrict__ E, float* __restrict__ C, int js)
{
    const int lm = blockIdx.y;
    const int i0 = blockIdx.x * 64;
    const float* Eb = E + (size_t)lm * 65536;
    float* Cb = C + (size_t)lm * 65536;
    __shared__ float As[64][65], Bs[64][65];
    const int t = threadIdx.x;
    const int ty = t >> 4, tx = t & 15;
    const int lv = t & 63, lw = t >> 6;
    float acc[4][4];
#pragma unroll
    for (int q=0;q<4;++q)
#pragma unroll
        for (int r=0;r<4;++r) acc[q][r]=0.f;
    for (int k0 = 0; k0 < 256; k0 += 64) {
        __syncthreads();
        for (int rr = 0; rr < 16; ++rr) {
            int kk = lw*16 + rr;
            As[kk][lv] = Eb[(k0+kk)*256 + i0 + lv];
            Bs[kk][lv] = Eb[(k0+kk)*256 + js + lv];
        }
        __syncthreads();
#pragma unroll 8
        for (int k = 0; k < 64; ++k) {
            float av[4], bv[4];
#pragma unroll
            for (int q=0;q<4;++q) av[q] = As[k][4*ty+q];
#pragma unroll
            for (int r=0;r<4;++r) bv[r] = Bs[k][4*tx+r];
#pragma unroll
            for (int q=0;q<4;++q)
#pragma unroll
                for (int r=0;r<4;++r) acc[q][r] = fmaf(av[q], bv[r], acc[q][r]);
        }
    }
#pragma unroll
    for (int q=0;q<4;++q)
#pragma unroll
        for (int r=0;r<4;++r)
            Cb[(i0 + 4*ty+q)*64 + 4*tx+r] = acc[q][r];
}

// X_s -= Q C: in-place update of E[:,js:js+64]. Block per (comp-tile, matrix).
__global__ __launch_bounds__(256)
void tp_gsU(float* __restrict__ E, const float* __restrict__ C, int js)
{
    const int lm = blockIdx.y;
    const int m0 = blockIdx.x * 64;
    float* Eb = E + (size_t)lm * 65536;
    const float* Cb = C + (size_t)lm * 65536;
    __shared__ float As[64][65], Bs[64][65];   // As[k][m], Bs[k][j]
    const int t = threadIdx.x;
    const int ty = t >> 4, tx = t & 15;
    const int lv = t & 63, lw = t >> 6;
    float acc[4][4];
#pragma unroll
    for (int q=0;q<4;++q)
#pragma unroll
        for (int r=0;r<4;++r) acc[q][r]=0.f;
    for (int k0 = 0; k0 < js; k0 += 64) {
        __syncthreads();
        for (int rr = 0; rr < 16; ++rr) {
            int mm = lw*16 + rr;
            As[lv][mm] = Eb[(m0+mm)*256 + k0 + lv];   // global coalesced over lv
            Bs[lw*16+rr][lv] = Cb[(k0 + lw*16+rr)*64 + lv];
        }
        __syncthreads();
#pragma unroll 8
        for (int k = 0; k < 64; ++k) {
            float av[4], bv[4];
#pragma unroll
            for (int q=0;q<4;++q) av[q] = As[k][4*ty+q];
#pragma unroll
            for (int r=0;r<4;++r) bv[r] = Bs[k][4*tx+r];
#pragma unroll
            for (int q=0;q<4;++q)
#pragma unroll
                for (int r=0;r<4;++r) acc[q][r] = fmaf(av[q], bv[r], acc[q][r]);
        }
    }
#pragma unroll
    for (int q=0;q<4;++q)
#pragma unroll
        for (int r=0;r<4;++r) {
            size_t idx = (size_t)(m0 + 4*ty+q)*256 + js + 4*tx+r;
            Eb[idx] -= acc[q][r];
        }
}

// In-strip shifted CholeskyQR2 (+ exact norm fix). One block per matrix.
#define CQ_XPITCH 260
#define CQ_LDS ((64*CQ_XPITCH + 64*65) * 4)   // 83,200 B

__global__ __launch_bounds__(256)
void tp_cholqr(float* __restrict__ E, int js)
{
    extern __shared__ float cls[];
    float* Xs = cls;                   // [64][260] vector-major (vec, comp)
    float* G  = cls + 64*CQ_XPITCH;    // [64][65]; col 64 = norm scratch
    const int lm = blockIdx.x;
    float* Eb = E + (size_t)lm*65536 + js;
    const int t = threadIdx.x, lv = t & 63, lw = t >> 6;
    const int ty = t >> 4, tx = t & 15;

    for (int ci = 0; ci < 64; ++ci) {
        int c = lw*64 + ci;
        Xs[lv*CQ_XPITCH + c] = Eb[(size_t)c*256 + lv];
    }
    __syncthreads();

    for (int sweep = 0; sweep < 2; ++sweep) {
        // ---- Gram G = Xs Xs^T (rows of Xs = vectors), 4x4 micro-tile ----
        float acc[4][4];
#pragma unroll
        for (int q=0;q<4;++q)
#pragma unroll
            for (int r=0;r<4;++r) acc[q][r]=0.f;
        for (int k = 0; k < 256; k += 4) {
            float4 a[4], b[4];
#pragma unroll
            for (int q=0;q<4;++q) a[q] = *(const float4*)&Xs[(4*ty+q)*CQ_XPITCH + k];
#pragma unroll
            for (int r=0;r<4;++r) b[r] = *(const float4*)&Xs[(4*tx+r)*CQ_XPITCH + k];
#pragma unroll
            for (int q=0;q<4;++q)
#pragma unroll
                for (int r=0;r<4;++r)
                    acc[q][r] += a[q].x*b[r].x + a[q].y*b[r].y
                               + a[q].z*b[r].z + a[q].w*b[r].w;
        }
#pragma unroll
        for (int q=0;q<4;++q)
#pragma unroll
            for (int r=0;r<4;++r)
                G[(4*ty+q)*65 + 4*tx+r] = acc[q][r] + ((4*ty+q)==(4*tx+r) ? 1e-6f : 0.f);
        __syncthreads();
        // ---- Cholesky (lower L), block-parallel ----
        for (int j = 0; j < 64; ++j) {
            float piv = fmaxf(G[j*65+j], 1e-12f);   // broadcast read
            float rjj = sqrtf(piv);
            float inv = 1.f / rjj;
            __syncthreads();
            if (t == j) G[j*65+j] = rjj;
            if (t < 64 && t > j) G[t*65+j] *= inv;
            __syncthreads();
            if (t < 64 && t > j) {
                float lij = G[t*65+j];
                for (int k2 = j+1; k2 <= t; ++k2)
                    G[t*65+k2] = fmaf(-lij, G[k2*65+j], G[t*65+k2]);
            }
            __syncthreads();
        }
        // ---- trsm: Q = X L^{-T}, per-comp forward substitution (no barriers) ----
        for (int j = 0; j < 64; ++j) {
            float s = Xs[j*CQ_XPITCH + t];
            for (int i = 0; i < j; ++i)
                s = fmaf(-G[j*65+i], Xs[i*CQ_XPITCH + t], s);
            Xs[j*CQ_XPITCH + t] = s * (1.f / G[j*65+j]);
        }
        __syncthreads();
    }
    // ---- exact per-vector norm fix ----
    {
        int v = t >> 2, p = t & 3;
        float nn = 0.f;
        for (int c = p*64; c < p*64 + 64; c += 4) {
            float4 xv = *(const float4*)&Xs[v*CQ_XPITCH + c];
            nn += xv.x*xv.x + xv.y*xv.y + xv.z*xv.z + xv.w*xv.w;
        }
        nn += __shfl_xor(nn, 1);
        nn += __shfl_xor(nn, 2);
        if (p == 0) G[v*65 + 64] = rsqrtf(fmaxf(nn, 1e-30f));
    }
    __syncthreads();
    {
        float scl = G[lv*65 + 64];
        for (int ci = 0; ci < 64; ++ci) {
            int c = lw*64 + ci;
            Eb[(size_t)c*256 + lv] = Xs[lv*CQ_XPITCH + c] * scl;
        }
    }
}

// ---------------------------------------------------------------------------
// Back-transform: G = H_0 ... H_253 E (apply reflectors in reverse order).
// Thread t owns column (t&255), rows (t>>8)*128..+127 in registers.
__global__ __launch_bounds__(512, 1)
void tp_backxf(float* __restrict__ E, const float* __restrict__ V,
               const float* __restrict__ taug)
{
    const int mat = blockIdx.x, t = threadIdx.x;
    const int j = t & 255, rh = t >> 8;
    float* Eb = E + (size_t)mat*65536;
    const float* Vb = V + (size_t)mat*32768;
    const float* taub = taug + mat*256;
    __shared__ __align__(16) float vbuf[2][256];
    __shared__ float part[2][256];
    __shared__ float taush[2];
    float Er[128];
#pragma unroll
    for (int r = 0; r < 128; ++r) Er[r] = Eb[(rh*128 + r)*256 + j];
    ((float*)vbuf)[t & 511] = 0.f;                 // zero both buffers (512 floats)
    __syncthreads();
    if (t < 2) vbuf[0][254 + t] = Vb[tp_voff(253) + t];
    if (t == 0) taush[0] = taub[253];
    for (int k = 253; k >= 0; --k) {
        const int cur = (253 - k) & 1;
        __syncthreads();                           // vbuf[cur]/taush[cur] ready
        const float tu = taush[cur];
        float p = 0.f;
#pragma unroll
        for (int blk = 0; blk < 8; ++blk) {
            const int rbase = rh*128 + blk*16;
            if (rbase + 15 > k) {                  // rows <= k read zeros anyway
#pragma unroll
                for (int q = 0; q < 16; q += 4) {
                    float4 v4 = *(const float4*)&vbuf[cur][rbase + q];
                    p = fmaf(Er[blk*16+q+0], v4.x, p);
                    p = fmaf(Er[blk*16+q+1], v4.y, p);
                    p = fmaf(Er[blk*16+q+2], v4.z, p);
                    p = fmaf(Er[blk*16+q+3], v4.w, p);
                }
            }
        }
        part[rh][j] = p;
        __syncthreads();
        const float sj = (part[0][j] + part[1][j]) * tu;
        if (k > 0) {                               // prefetch next reflector
            const int kn = k - 1, len = 255 - kn, vo = tp_voff(kn);
            for (int idx = t; idx < len; idx += 512)
                vbuf[cur^1][kn+1+idx] = Vb[vo + idx];
            if (t == 0) taush[cur^1] = taub[kn];
        }
#pragma unroll
        for (int blk = 0; blk < 8; ++blk) {
            const int rbase = rh*128 + blk*16;
            if (rbase + 15 > k) {
#pragma unroll
                for (int q = 0; q < 16; q += 4) {
                    float4 v4 = *(const float4*)&vbuf[cur][rbase + q];
                    Er[blk*16+q+0] = fmaf(-sj, v4.x, Er[blk*16+q+0]);
                    Er[blk*16+q+1] = fmaf(-sj, v4.y, Er[blk*16+q+1]);
                    Er[blk*16+q+2] = fmaf(-sj, v4.z, Er[blk*16+q+2]);
                    Er[blk*16+q+3] = fmaf(-sj, v4.w, Er[blk*16+q+3]);
                }
            }
        }
    }
#pragma unroll
    for (int r = 0; r < 128; ++r) Eb[(rh*128 + r)*256 + j] = Er[r];
}

// ---------------------------------------------------------------------------
// fp32 128x128-tile GEMMs (256 thr, 8x8 micro-tile, K-step 16)
#define GEMM_PROLOGUE(Aptr, Bptr)                                              \
    __shared__ __align__(16) float As[16][132];                                \
    __shared__ __align__(16) float Bs[16][132];                                \
    const int t = threadIdx.x, tx = t & 15, ty = t >> 4;                       \
    const int li = t >> 1, lk = (t & 1) * 8;                                   \
    const int bk = t >> 4, bj = (t & 15) * 8;                                  \
    float acc[8][8];                                                           \
    _Pragma("unroll") for (int q = 0; q < 8; ++q)                              \
    _Pragma("unroll") for (int r2 = 0; r2 < 8; ++r2) acc[q][r2] = 0.f;

#define GEMM_INNER                                                             \
    _Pragma("unroll")                                                          \
    for (int kk = 0; kk < 16; ++kk) {                                          \
        float4 av0 = *(const float4*)&As[kk][ty*8];                            \
        float4 av1 = *(const float4*)&As[kk][ty*8+4];                          \
        float4 bv0 = *(const float4*)&Bs[kk][tx*8];                            \
        float4 bv1 = *(const float4*)&Bs[kk][tx*8+4];                          \
        float av[8] = {av0.x,av0.y,av0.z,av0.w,av1.x,av1.y,av1.z,av1.w};       \
        float bw[8] = {bv0.x,bv0.y,bv0.z,bv0.w,bv1.x,bv1.y,bv1.z,bv1.w};       \
        _Pragma("unroll") for (int q = 0; q < 8; ++q)                          \
        _Pragma("unroll") for (int r2 = 0; r2 < 8; ++r2)                       \
            acc[q][r2] = fmaf(av[q], bw[r2], acc[q][r2]);                      \
    }

// P[lm] = x_b @ S_c,  gm = mat0 + lm
__global__ __launch_bounds__(256)
void tp_gemm_xS(const float* __restrict__ X, const float* __restrict__ S,
                float* __restrict__ P, int mat0)
{
    const int lm = blockIdx.y, gm = mat0 + lm, b = gm >> 2, c = gm & 3;
    const int i0 = (blockIdx.x >> 1) * 128, j0 = (blockIdx.x & 1) * 128;
    const float* Ag = X + (size_t)b * 65536;
    const float* Bg = S + (size_t)c * 65536;
    float* Cg = P + (size_t)lm * 65536;
    GEMM_PROLOGUE(Ag, Bg)
    for (int k0 = 0; k0 < 256; k0 += 16) {
        float4 a0 = *(const float4*)&Ag[(i0+li)*256 + k0 + lk];
        float4 a1 = *(const float4*)&Ag[(i0+li)*256 + k0 + lk + 4];
        float4 b0 = *(const float4*)&Bg[(k0+bk)*256 + j0 + bj];
        float4 b1 = *(const float4*)&Bg[(k0+bk)*256 + j0 + bj + 4];
        __syncthreads();
        As[lk+0][li]=a0.x; As[lk+1][li]=a0.y; As[lk+2][li]=a0.z; As[lk+3][li]=a0.w;
        As[lk+4][li]=a1.x; As[lk+5][li]=a1.y; As[lk+6][li]=a1.z; As[lk+7][li]=a1.w;
        *(float4*)&Bs[bk][bj] = b0;  *(float4*)&Bs[bk][bj+4] = b1;
        __syncthreads();
        GEMM_INNER
    }
#pragma unroll
    for (int q = 0; q < 8; ++q) {
        float4 o0 = {acc[q][0],acc[q][1],acc[q][2],acc[q][3]};
        float4 o1 = {acc[q][4],acc[q][5],acc[q][6],acc[q][7]};
        *(float4*)&Cg[(i0+ty*8+q)*256 + j0 + tx*8]     = o0;
        *(float4*)&Cg[(i0+ty*8+q)*256 + j0 + tx*8 + 4] = o1;
    }
}

// M[lm] = 0.95 * S_c @ P[lm] + 0.05 I -> permuted layout (Mout pre-offset;
// requires mat0 % 4 == 0 so c = lm & 3)
__global__ __launch_bounds__(256)
void tp_gemm_SP(const float* __restrict__ S, const float* __restrict__ P,
                float* __restrict__ Mout)
{
    const int lm = blockIdx.y, c = lm & 3;
    const int i0 = (blockIdx.x >> 1) * 128, j0 = (blockIdx.x & 1) * 128;
    const float* Ag = S + (size_t)c * 65536;
    const float* Bg = P + (size_t)lm * 65536;
    float* Mb = Mout + (size_t)lm * 65536;
    GEMM_PROLOGUE(Ag, Bg)
    for (int k0 = 0; k0 < 256; k0 += 16) {
        float4 a0 = *(const float4*)&Ag[(i0+li)*256 + k0 + lk];
        float4 a1 = *(const float4*)&Ag[(i0+li)*256 + k0 + lk + 4];
        float4 b0 = *(const float4*)&Bg[(k0+bk)*256 + j0 + bj];
        float4 b1 = *(const float4*)&Bg[(k0+bk)*256 + j0 + bj + 4];
        __syncthreads();
        As[lk+0][li]=a0.x; As[lk+1][li]=a0.y; As[lk+2][li]=a0.z; As[lk+3][li]=a0.w;
        As[lk+4][li]=a1.x; As[lk+5][li]=a1.y; As[lk+6][li]=a1.z; As[lk+7][li]=a1.w;
        *(float4*)&Bs[bk][bj] = b0;  *(float4*)&Bs[bk][bj+4] = b1;
        __syncthreads();
        GEMM_INNER
    }
#pragma unroll
    for (int q = 0; q < 8; ++q) {
        const int i = i0 + ty*8 + q;
        const int jb = j0 + tx*8;
        const int tt = i + ((jb >> 7) << 8);
        float* dst = Mb + ((jb & 127) >> 2) * 2048 + tt * 4;
        float4 o0, o1;
        o0.x = 0.95f*acc[q][0] + ((i == jb+0) ? 0.05f : 0.f);
        o0.y = 0.95f*acc[q][1] + ((i == jb+1) ? 0.05f : 0.f);
        o0.z = 0.95f*acc[q][2] + ((i == jb+2) ? 0.05f : 0.f);
        o0.w = 0.95f*acc[q][3] + ((i == jb+3) ? 0.05f : 0.f);
        o1.x = 0.95f*acc[q][4] + ((i == jb+4) ? 0.05f : 0.f);
        o1.y = 0.95f*acc[q][5] + ((i == jb+5) ? 0.05f : 0.f);
        o1.z = 0.95f*acc[q][6] + ((i == jb+6) ? 0.05f : 0.f);
        o1.w = 0.95f*acc[q][7] + ((i == jb+7) ? 0.05f : 0.f);
        *(float4*)dst = o0;
        *(float4*)(dst + 2048) = o1;
    }
}

// Out[lm] = (G * diag(f(lam))) @ G^T   (fmode=1: rsqrt, fmode=0: log)
__global__ __launch_bounds__(256)
void tp_recon(const float* __restrict__ G, const float* __restrict__ lam,
              float* __restrict__ Out, int fmode)
{
    const int lm = blockIdx.y;
    const int i0 = (blockIdx.x >> 1) * 128, j0 = (blockIdx.x & 1) * 128;
    const float* Gb = G + (size_t)lm * 65536;
    float* Ob = Out + (size_t)lm * 65536;
    __shared__ float f[256];
    GEMM_PROLOGUE(Gb, Gb)
    {
        float l0 = fmaxf(lam[lm*256 + t], 1e-8f);
        f[t] = fmode ? rsqrtf(l0) : logf(l0);
    }
    for (int k0 = 0; k0 < 256; k0 += 16) {
        float4 a0 = *(const float4*)&Gb[(i0+li)*256 + k0 + lk];
        float4 a1 = *(const float4*)&Gb[(i0+li)*256 + k0 + lk + 4];
        float4 b0 = *(const float4*)&Gb[(j0+li)*256 + k0 + lk];
        float4 b1 = *(const float4*)&Gb[(j0+li)*256 + k0 + lk + 4];
        __syncthreads();
        As[lk+0][li]=a0.x*f[k0+lk+0]; As[lk+1][li]=a0.y*f[k0+lk+1];
        As[lk+2][li]=a0.z*f[k0+lk+2]; As[lk+3][li]=a0.w*f[k0+lk+3];
        As[lk+4][li]=a1.x*f[k0+lk+4]; As[lk+5][li]=a1.y*f[k0+lk+5];
        As[lk+6][li]=a1.z*f[k0+lk+6]; As[lk+7][li]=a1.w*f[k0+lk+7];
        Bs[lk+0][li]=b0.x; Bs[lk+1][li]=b0.y; Bs[lk+2][li]=b0.z; Bs[lk+3][li]=b0.w;
        Bs[lk+4][li]=b1.x; Bs[lk+5][li]=b1.y; Bs[lk+6][li]=b1.z; Bs[lk+7][li]=b1.w;
        __syncthreads();
        GEMM_INNER
    }
#pragma unroll
    for (int q = 0; q < 8; ++q) {
        float4 o0 = {acc[q][0],acc[q][1],acc[q][2],acc[q][3]};
        float4 o1 = {acc[q][4],acc[q][5],acc[q][6],acc[q][7]};
        *(float4*)&Ob[(i0+ty*8+q)*256 + j0 + tx*8]     = o0;
        *(float4*)&Ob[(i0+ty*8+q)*256 + j0 + tx*8 + 4] = o1;
    }
}

// ---------------------------------------------------------------------------
static void tp_orth(float* E, float* Csc, int nmat, hipStream_t stream)
{
    for (int s = 0; s < 4; ++s) {
        const int js = s * 64;
        if (s > 0) {
            tp_gsC<<<dim3(s, nmat), 256, 0, stream>>>(E, Csc, js);
            tp_gsU<<<dim3(4, nmat), 256, 0, stream>>>(E, Csc, js);
        }
        tp_cholqr<<<nmat, 256, CQ_LDS, stream>>>(E, js);
    }
}

extern "C" void kernel_launch(void* const* d_in, const int* in_sizes, int n_in,
                              void* d_out, int out_size, void* d_ws, size_t ws_size,
                              hipStream_t stream)
{
    (void)in_sizes; (void)n_in; (void)out_size;
    const float* x = (const float*)d_in[0];     // (256,256,256)
    const float* w = (const float*)d_in[1];     // (4,256,256)
    float* out = (float*)d_out;                 // (256,4,256,256)
    float* ws  = (float*)d_ws;

    // ---- pick largest chunk size CS fitting ws_size (pure fn of ws_size:
    //      identical launch sequence every call -> graph-capture safe) ----
    int CS = 1024;
    while (CS > 4) {
        size_t need = 4ull * (524288ull + (size_t)CS * 99328ull);
        if (need <= ws_size) break;
        CS >>= 1;
    }

    float* S    = ws;                            // 4*65536
    float* Wp   = S    + (size_t)4*65536;        // 4*65536
    float* V    = Wp   + (size_t)4*65536;        // CS*32768
    float* tau  = V    + (size_t)CS*32768;       // CS*256
    float* dd   = tau  + (size_t)CS*256;
    float* ee   = dd   + (size_t)CS*256;
    float* lamb = ee   + (size_t)CS*256;
    float* EG   = lamb + (size_t)CS*256;         // CS*65536

    const int INVIT_LDS = 33280 * 4;   // 133120 B dynamic LDS
    hipFuncSetAttribute(reinterpret_cast<const void*>(tp_invit),
                        hipFuncAttributeMaxDynamicSharedMemorySize, INVIT_LDS);
    hipFuncSetAttribute(reinterpret_cast<const void*>(tp_cholqr),
                        hipFuncAttributeMaxDynamicSharedMemorySize, CQ_LDS);

    // ---- weight branch: S_c = (0.95 W + 0.05 I)^(-1/2), 4 matrices ----
    // (out is free scratch until the main loop writes it)
    tp_regw<<<1024, 256, 0, stream>>>(w, Wp);
    tp_tridiag<<<4, 512, 0, stream>>>(Wp, V, tau, dd, ee);
    tp_bisect <<<4, 256, 0, stream>>>(dd, ee, lamb);
    tp_invit  <<<16, 64, INVIT_LDS, stream>>>(dd, ee, lamb, EG);
    tp_orth(EG, out, 4, stream);
    tp_backxf <<<4, 512, 0, stream>>>(EG, V, tau);
    tp_recon  <<<dim3(4,4), 256, 0, stream>>>(EG, lamb, S, 1);

    // ---- main branch in chunks of CS matrices ----
    for (int mat0 = 0; mat0 < 1024; mat0 += CS) {
        float* outc = out + (size_t)mat0 * 65536;
        // congruence: M = 0.95 S x S + 0.05 I (M -> d_out chunk, perm layout)
        tp_gemm_xS<<<dim3(4,CS), 256, 0, stream>>>(x, S, EG, mat0);   // P = x S
        tp_gemm_SP<<<dim3(4,CS), 256, 0, stream>>>(S, EG, outc);      // M
        // eig + log reconstruction (outc doubles as C-scratch: M dead after tridiag)
        tp_tridiag<<<CS, 512, 0, stream>>>(outc, V, tau, dd, ee);
        tp_bisect <<<CS, 256, 0, stream>>>(dd, ee, lamb);
        tp_invit  <<<CS*4, 64, INVIT_LDS, stream>>>(dd, ee, lamb, EG);
        tp_orth(EG, outc, CS, stream);
        tp_backxf <<<CS, 512, 0, stream>>>(EG, V, tau);
        tp_recon  <<<dim3(4,CS), 256, 0, stream>>>(EG, lamb, outc, 0);
    }
}